// Round 1
// baseline (726.878 us; speedup 1.0000x reference)
//
#include <hip/hip_runtime.h>
#include <hip/hip_bf16.h>
#include <math.h>

#define T_SEQ 2048
#define C_DIM 768
#define NH    12
#define HD    64
#define QKV_N 2304
#define BQ    32

// ---------------- RoPE tables: ctab/stab[t][i], i<32 ----------------
__global__ __launch_bounds__(256) void rope_table_kernel(float* __restrict__ ctab,
                                                         float* __restrict__ stab) {
    int idx = blockIdx.x * 256 + threadIdx.x;      // 0..65535
    if (idx >= T_SEQ * 32) return;
    int p = idx >> 5;
    int i = idx & 31;
    // inv_freq = 10000^(-i/32) = exp2(-i/32 * log2(10000))
    float invf = exp2f(-(float)i * (0.03125f * 13.287712379549449f));
    float f = (float)p * invf;
    ctab[idx] = cosf(f);
    stab[idx] = sinf(f);
}

// ---------------- fp32 tiled GEMM: C[M][N] = A[M][K] @ B[K][N] + bias[N] ----
__global__ __launch_bounds__(256) void gemm_bias_kernel(
    const float* __restrict__ A, const float* __restrict__ B,
    const float* __restrict__ bias, float* __restrict__ C,
    int M, int N, int K) {
    __shared__ float As[16][68];   // [k][m], stride 68 -> 16B-aligned 4-vec reads
    __shared__ float Bs[16][68];   // [k][n]
    int tid = threadIdx.x;
    int tx = tid & 15, ty = tid >> 4;
    int bm = blockIdx.y, bn = blockIdx.x;
    const float* Ab = A + (size_t)bm * 64 * K;
    const float* Bb = B + (size_t)bn * 64;
    float acc[4][4] = {};
    for (int k0 = 0; k0 < K; k0 += 16) {
        #pragma unroll
        for (int e = 0; e < 4; ++e) {          // A: 64 rows x 16 k
            int idx = e * 256 + tid;
            int m = idx >> 4, kk = idx & 15;
            As[kk][m] = Ab[(size_t)m * K + k0 + kk];
        }
        #pragma unroll
        for (int e = 0; e < 4; ++e) {          // B: 16 k x 64 cols
            int idx = e * 256 + tid;
            int kk = idx >> 6, n = idx & 63;
            Bs[kk][n] = Bb[(size_t)(k0 + kk) * N + n];
        }
        __syncthreads();
        #pragma unroll
        for (int kk = 0; kk < 16; ++kk) {
            float a[4], b[4];
            #pragma unroll
            for (int i = 0; i < 4; ++i) a[i] = As[kk][ty * 4 + i];
            #pragma unroll
            for (int j = 0; j < 4; ++j) b[j] = Bs[kk][tx * 4 + j];
            #pragma unroll
            for (int i = 0; i < 4; ++i)
                #pragma unroll
                for (int j = 0; j < 4; ++j)
                    acc[i][j] = fmaf(a[i], b[j], acc[i][j]);
        }
        __syncthreads();
    }
    #pragma unroll
    for (int i = 0; i < 4; ++i) {
        int row = bm * 64 + ty * 4 + i;
        #pragma unroll
        for (int j = 0; j < 4; ++j) {
            int col = bn * 64 + tx * 4 + j;
            C[(size_t)row * N + col] = acc[i][j] + bias[col];
        }
    }
}

// ---------------- split qkv + RoPE into head-major Q/K/V [h][t][d] --------
__global__ __launch_bounds__(256) void split_rope_kernel(
    const float* __restrict__ qkv, const float* __restrict__ ctab,
    const float* __restrict__ stab, float* __restrict__ Q,
    float* __restrict__ K, float* __restrict__ V) {
    int t = blockIdx.x;
    int tid = threadIdx.x;
    const float* row = qkv + (size_t)t * QKV_N;
    #pragma unroll
    for (int e = 0; e < 9; ++e) {
        int idx = e * 256 + tid;               // 0..2303
        int tensor = idx / 768;
        int hd = idx - tensor * 768;
        int h = hd >> 6;
        int d = hd & 63;
        float v = row[idx];
        size_t dst = ((size_t)h * T_SEQ + t) * HD + d;
        if (tensor == 2) {
            V[dst] = v;
        } else {
            float out;
            if (d < 32) {
                float part = row[idx + 32];
                out = v * ctab[t * 32 + d] - part * stab[t * 32 + d];
            } else {
                int i = d - 32;
                float part = row[idx - 32];
                out = v * ctab[t * 32 + i] + part * stab[t * 32 + i];
            }
            if (tensor == 0) Q[dst] = out; else K[dst] = out;
        }
    }
}

// ---------------- causal flash attention, fp32 ----------------------------
// block = 256 threads; one block per (head, 32-query tile).
// thread tid: row r = tid>>3 (32 rows), group g = tid&7; owns dims g*8..g*8+7.
__global__ __launch_bounds__(256) void attn_kernel(
    const float* __restrict__ Q, const float* __restrict__ K,
    const float* __restrict__ V, float* __restrict__ Y) {
    __shared__ float Qs[BQ][65];   // stride 65: score reads hit 8 distinct banks
    __shared__ float Ks[BQ][65];
    __shared__ float Vs[BQ][65];
    __shared__ float Ss[BQ][33];
    int tid = threadIdx.x;
    int h = blockIdx.y;
    int qt0 = blockIdx.x * BQ;
    const float scale = 0.125f;    // 1/sqrt(64)
    const float* Qh = Q + (size_t)h * T_SEQ * HD;
    const float* Kh = K + (size_t)h * T_SEQ * HD;
    const float* Vh = V + (size_t)h * T_SEQ * HD;
    #pragma unroll
    for (int e = 0; e < 8; ++e) {
        int idx = e * 256 + tid;
        int r = idx >> 6, d = idx & 63;
        Qs[r][d] = Qh[(size_t)(qt0 + r) * HD + d] * scale;
    }
    int r = tid >> 3;
    int g = tid & 7;
    float o[8] = {};
    float m = -INFINITY, l = 0.f;
    int j0 = g * 4;
    int nkt = blockIdx.x + 1;
    for (int kt = 0; kt < nkt; ++kt) {
        int k0 = kt * BQ;
        __syncthreads();                       // prev PV done before restage
        #pragma unroll
        for (int e = 0; e < 8; ++e) {
            int idx = e * 256 + tid;
            int rr = idx >> 6, d = idx & 63;
            Ks[rr][d] = Kh[(size_t)(k0 + rr) * HD + d];
            Vs[rr][d] = Vh[(size_t)(k0 + rr) * HD + d];
        }
        __syncthreads();
        // scores: this thread computes S[r][j0..j0+3]
        float s0 = 0.f, s1 = 0.f, s2 = 0.f, s3 = 0.f;
        #pragma unroll
        for (int d = 0; d < 64; ++d) {
            float qv = Qs[r][d];
            s0 = fmaf(qv, Ks[j0 + 0][d], s0);
            s1 = fmaf(qv, Ks[j0 + 1][d], s1);
            s2 = fmaf(qv, Ks[j0 + 2][d], s2);
            s3 = fmaf(qv, Ks[j0 + 3][d], s3);
        }
        int q_idx = qt0 + r;
        float s[4] = {s0, s1, s2, s3};
        float smax = -INFINITY;
        #pragma unroll
        for (int jj = 0; jj < 4; ++jj) {
            if (k0 + j0 + jj > q_idx) s[jj] = -INFINITY;
            smax = fmaxf(smax, s[jj]);
        }
        #pragma unroll
        for (int off = 1; off < 8; off <<= 1)
            smax = fmaxf(smax, __shfl_xor(smax, off, 8));
        float mnew = fmaxf(m, smax);
        float alpha = __expf(m - mnew);        // m=-inf first iter -> 0
        float psum = 0.f;
        #pragma unroll
        for (int jj = 0; jj < 4; ++jj) {
            float p = __expf(s[jj] - mnew);    // masked -> exp(-inf)=0
            Ss[r][j0 + jj] = p;
            psum += p;
        }
        #pragma unroll
        for (int off = 1; off < 8; off <<= 1)
            psum += __shfl_xor(psum, off, 8);
        l = l * alpha + psum;
        m = mnew;
        #pragma unroll
        for (int dd = 0; dd < 8; ++dd) o[dd] *= alpha;
        __syncthreads();                       // Ss visible to whole block
        #pragma unroll
        for (int j = 0; j < BQ; ++j) {
            float p = Ss[r][j];
            #pragma unroll
            for (int dd = 0; dd < 8; ++dd)
                o[dd] = fmaf(p, Vs[j][g * 8 + dd], o[dd]);
        }
    }
    float inv_l = 1.f / l;
    int t = qt0 + r;
    #pragma unroll
    for (int dd = 0; dd < 8; ++dd)
        Y[(size_t)t * C_DIM + h * HD + g * 8 + dd] = o[dd] * inv_l;
}

extern "C" void kernel_launch(void* const* d_in, const int* in_sizes, int n_in,
                              void* d_out, int out_size, void* d_ws, size_t ws_size,
                              hipStream_t stream) {
    const float* x      = (const float*)d_in[0];
    const float* w_qkv  = (const float*)d_in[1];
    const float* b_qkv  = (const float*)d_in[2];
    const float* w_proj = (const float*)d_in[3];
    const float* b_proj = (const float*)d_in[4];
    float* out = (float*)d_out;

    float* ws   = (float*)d_ws;
    float* qkv  = ws;                                  // 2048*2304 floats
    float* y    = ws;                                  // reuse qkv region (dead after split)
    float* Qh   = qkv + (size_t)T_SEQ * QKV_N;         // 12*2048*64 each
    float* Kh   = Qh + (size_t)NH * T_SEQ * HD;
    float* Vh   = Kh + (size_t)NH * T_SEQ * HD;
    float* ctab = Vh + (size_t)NH * T_SEQ * HD;        // 2048*32
    float* stab = ctab + T_SEQ * 32;                   // total ~9.57M floats (~38MB)

    rope_table_kernel<<<256, 256, 0, stream>>>(ctab, stab);

    dim3 g1(QKV_N / 64, T_SEQ / 64);
    gemm_bias_kernel<<<g1, 256, 0, stream>>>(x, w_qkv, b_qkv, qkv, T_SEQ, QKV_N, C_DIM);

    split_rope_kernel<<<T_SEQ, 256, 0, stream>>>(qkv, ctab, stab, Qh, Kh, Vh);

    dim3 g3(T_SEQ / BQ, NH);
    attn_kernel<<<g3, 256, 0, stream>>>(Qh, Kh, Vh, y);

    dim3 g4(C_DIM / 64, T_SEQ / 64);
    gemm_bias_kernel<<<g4, 256, 0, stream>>>(y, w_proj, b_proj, out, T_SEQ, C_DIM, C_DIM);
}

// Round 2
// 232.937 us; speedup vs baseline: 3.1205x; 3.1205x over previous
//
#include <hip/hip_runtime.h>
#include <hip/hip_bf16.h>
#include <math.h>

#define T_SEQ 2048
#define C_DIM 768
#define NH    12
#define HD    64
#define QKV_N 2304

typedef __attribute__((ext_vector_type(8))) short short8;
typedef __attribute__((ext_vector_type(4))) float f32x4;
typedef __hip_bfloat16 bf16;

static __device__ __forceinline__ unsigned int f2bf(float x) {
    bf16 b = __float2bfloat16(x);
    return (unsigned int)*reinterpret_cast<unsigned short*>(&b);
}

// ---------------- RoPE tables: ctab/stab[t][i], i<32 ----------------
__global__ __launch_bounds__(256) void rope_table_kernel(float* __restrict__ ctab,
                                                         float* __restrict__ stab) {
    int idx = blockIdx.x * 256 + threadIdx.x;      // 0..65535
    if (idx >= T_SEQ * 32) return;
    int p = idx >> 5;
    int i = idx & 31;
    float invf = exp2f(-(float)i * (0.03125f * 13.287712379549449f));
    float f = (float)p * invf;
    ctab[idx] = cosf(f);
    stab[idx] = sinf(f);
}

// ---------------- fp32 tiled GEMM: C[M][N] = A[M][K] @ B[K][N] + bias[N] ----
__global__ __launch_bounds__(256) void gemm_bias_kernel(
    const float* __restrict__ A, const float* __restrict__ B,
    const float* __restrict__ bias, float* __restrict__ C,
    int M, int N, int K) {
    __shared__ float As[16][68];
    __shared__ float Bs[16][68];
    int tid = threadIdx.x;
    int tx = tid & 15, ty = tid >> 4;
    int bm = blockIdx.y, bn = blockIdx.x;
    const float* Ab = A + (size_t)bm * 64 * K;
    const float* Bb = B + (size_t)bn * 64;
    float acc[4][4] = {};
    for (int k0 = 0; k0 < K; k0 += 16) {
        #pragma unroll
        for (int e = 0; e < 4; ++e) {
            int idx = e * 256 + tid;
            int m = idx >> 4, kk = idx & 15;
            As[kk][m] = Ab[(size_t)m * K + k0 + kk];
        }
        #pragma unroll
        for (int e = 0; e < 4; ++e) {
            int idx = e * 256 + tid;
            int kk = idx >> 6, n = idx & 63;
            Bs[kk][n] = Bb[(size_t)(k0 + kk) * N + n];
        }
        __syncthreads();
        #pragma unroll
        for (int kk = 0; kk < 16; ++kk) {
            float a[4], b[4];
            #pragma unroll
            for (int i = 0; i < 4; ++i) a[i] = As[kk][ty * 4 + i];
            #pragma unroll
            for (int j = 0; j < 4; ++j) b[j] = Bs[kk][tx * 4 + j];
            #pragma unroll
            for (int i = 0; i < 4; ++i)
                #pragma unroll
                for (int j = 0; j < 4; ++j)
                    acc[i][j] = fmaf(a[i], b[j], acc[i][j]);
        }
        __syncthreads();
    }
    #pragma unroll
    for (int i = 0; i < 4; ++i) {
        int row = bm * 64 + ty * 4 + i;
        #pragma unroll
        for (int j = 0; j < 4; ++j) {
            int col = bn * 64 + tx * 4 + j;
            C[(size_t)row * N + col] = acc[i][j] + bias[col];
        }
    }
}

// ---------------- split qkv + RoPE -> bf16 head-major Q/K/V [h][t][d] ------
// Q is pre-scaled by 1/sqrt(HD).
__global__ __launch_bounds__(256) void split_rope_kernel(
    const float* __restrict__ qkv, const float* __restrict__ ctab,
    const float* __restrict__ stab, bf16* __restrict__ Q,
    bf16* __restrict__ K, bf16* __restrict__ V) {
    int t = blockIdx.x;
    int tid = threadIdx.x;
    const float* row = qkv + (size_t)t * QKV_N;
    #pragma unroll
    for (int e = 0; e < 9; ++e) {
        int idx = e * 256 + tid;               // 0..2303
        int tensor = idx / 768;
        int hd = idx - tensor * 768;
        int h = hd >> 6;
        int d = hd & 63;
        float v = row[idx];
        size_t dst = ((size_t)h * T_SEQ + t) * HD + d;
        if (tensor == 2) {
            V[dst] = __float2bfloat16(v);
        } else {
            float out;
            if (d < 32) {
                float part = row[idx + 32];
                out = v * ctab[t * 32 + d] - part * stab[t * 32 + d];
            } else {
                int i = d - 32;
                float part = row[idx - 32];
                out = v * ctab[t * 32 + i] + part * stab[t * 32 + i];
            }
            if (tensor == 0) Q[dst] = __float2bfloat16(out * 0.125f);
            else             K[dst] = __float2bfloat16(out);
        }
    }
}

// ---------------- causal flash attention, bf16 MFMA ------------------------
// Block: 256 thr = 4 waves. Wave w owns q-rows [qt0+16w, qt0+16w+16). BK=64.
// Swapped QK^T: S^T = mfma(K, Q) -> lane holds S[q=lane&15][16 kv values].
// PV via P round-trip through per-wave LDS (A-frag layout) and transposed V.
__global__ __launch_bounds__(256) void attn_mfma_kernel(
    const bf16* __restrict__ Qp, const bf16* __restrict__ Kp,
    const bf16* __restrict__ Vp, float* __restrict__ Y) {
    __shared__ __align__(16) short Ks[64 * 64];     // [kv][d], 16B-chunk XOR swizzle
    __shared__ __align__(16) short Vt[64 * 64];     // [d][kv], swizzled
    __shared__ __align__(16) short Pl[4][16 * 64];  // per-wave P [q][kv], swizzled

    int tid = threadIdx.x;
    int w  = tid >> 6;
    int l  = tid & 63;
    int lr = l & 15;
    int lg = l >> 4;
    int h  = blockIdx.y;
    int qt0 = blockIdx.x * 64;

    const short* Qg = (const short*)(Qp + (size_t)h * T_SEQ * HD);
    const short* Kg = (const short*)(Kp + (size_t)h * T_SEQ * HD);
    const short* Vg = (const short*)(Vp + (size_t)h * T_SEQ * HD);

    // Q B-frags (dims 0-31, 32-63), held in regs for the whole kernel
    int qrow = qt0 + w * 16 + lr;
    short8 qf0 = *(const short8*)(Qg + (size_t)qrow * HD + lg * 8);
    short8 qf1 = *(const short8*)(Qg + (size_t)qrow * HD + 32 + lg * 8);

    f32x4 o[4] = {};                    // o[nt]: rows q=lg*4+reg, col nt*16+lr
    float m = -INFINITY, lsum = 0.f;
    int nkt = blockIdx.x + 1;

    for (int kt = 0; kt < nkt; ++kt) {
        int k0 = kt * 64;
        __syncthreads();                 // everyone done with prev K/V tiles
        {
            int chunk = tid & 7;
            int kv = tid >> 3;           // 0..31
            #pragma unroll
            for (int e = 0; e < 2; ++e) {
                int kkv = kv + e * 32;
                short8 kd = *(const short8*)(Kg + (size_t)(k0 + kkv) * HD + chunk * 8);
                *(short8*)(&Ks[kkv * 64 + ((chunk ^ (kkv & 7)) << 3)]) = kd;
            }
            // V transposed: thread handles kv pair (2*kvp, 2*kvp+1) x 8 dims
            int kvp = tid >> 3;
            short8 v0 = *(const short8*)(Vg + (size_t)(k0 + 2 * kvp) * HD + chunk * 8);
            short8 v1 = *(const short8*)(Vg + (size_t)(k0 + 2 * kvp + 1) * HD + chunk * 8);
            #pragma unroll
            for (int j = 0; j < 8; ++j) {
                int dim = chunk * 8 + j;
                unsigned int pk = (unsigned int)(unsigned short)v0[j]
                                | ((unsigned int)(unsigned short)v1[j] << 16);
                *(unsigned int*)(&Vt[dim * 64 + (((kvp >> 2) ^ (dim & 7)) << 3)
                                     + (kvp & 3) * 2]) = pk;
            }
        }
        __syncthreads();

        // QK^T (swapped): c[mt] = S^T tile rows kv=[16mt,16mt+16), cols q of wave
        f32x4 c[4];
        #pragma unroll
        for (int mt = 0; mt < 4; ++mt) {
            c[mt] = (f32x4){0.f, 0.f, 0.f, 0.f};
            int row = mt * 16 + lr;
            #pragma unroll
            for (int ks = 0; ks < 2; ++ks) {
                short8 af = *(const short8*)(&Ks[row * 64 + (((ks * 4 + lg) ^ (row & 7)) << 3)]);
                c[mt] = __builtin_amdgcn_mfma_f32_16x16x32_bf16(af, ks ? qf1 : qf0, c[mt], 0, 0, 0);
            }
        }

        // mask + online softmax (per lane: q-row lr, 16 kv values)
        int qg = qt0 + w * 16 + lr;
        float p[16];
        float smax = -INFINITY;
        #pragma unroll
        for (int mt = 0; mt < 4; ++mt)
            #pragma unroll
            for (int r = 0; r < 4; ++r) {
                float s = c[mt][r];
                int kvg = k0 + mt * 16 + lg * 4 + r;
                if (kvg > qg) s = -INFINITY;
                p[mt * 4 + r] = s;
                smax = fmaxf(smax, s);
            }
        smax = fmaxf(smax, __shfl_xor(smax, 16));
        smax = fmaxf(smax, __shfl_xor(smax, 32));
        float mnew = fmaxf(m, smax);
        float alpha = __expf(m - mnew);       // first tile: exp(-inf)=0
        float ps = 0.f;
        #pragma unroll
        for (int i = 0; i < 16; ++i) { p[i] = __expf(p[i] - mnew); ps += p[i]; }
        ps += __shfl_xor(ps, 16);
        ps += __shfl_xor(ps, 32);
        lsum = lsum * alpha + ps;
        m = mnew;

        // rescale O: stats live at lane (q&15); O rows are lg*4+reg
        #pragma unroll
        for (int r = 0; r < 4; ++r) {
            float ar = __shfl(alpha, lg * 4 + r);
            #pragma unroll
            for (int nt = 0; nt < 4; ++nt) o[nt][r] *= ar;
        }

        // write P (bf16) to per-wave LDS in A-frag-readable layout [q][kv]
        short* Pw = &Pl[w][0];
        #pragma unroll
        for (int mt = 0; mt < 4; ++mt)
            #pragma unroll
            for (int rh = 0; rh < 2; ++rh) {
                unsigned int u = f2bf(p[mt * 4 + 2 * rh]) | (f2bf(p[mt * 4 + 2 * rh + 1]) << 16);
                int chunk = 2 * mt + (lg >> 1);
                *(unsigned int*)(&Pw[lr * 64 + ((chunk ^ (lr & 7)) << 3)
                                     + 4 * (lg & 1) + 2 * rh]) = u;
            }
        asm volatile("" ::: "memory");   // keep P writes before the reads below

        // PV: O[q][dim] += P[q][kv] * V[kv][dim]
        #pragma unroll
        for (int ks = 0; ks < 2; ++ks) {
            short8 pf = *(const short8*)(&Pw[lr * 64 + (((ks * 4 + lg) ^ (lr & 7)) << 3)]);
            #pragma unroll
            for (int nt = 0; nt < 4; ++nt) {
                int vrow = nt * 16 + lr;
                short8 vf = *(const short8*)(&Vt[vrow * 64 + (((ks * 4 + lg) ^ (vrow & 7)) << 3)]);
                o[nt] = __builtin_amdgcn_mfma_f32_16x16x32_bf16(pf, vf, o[nt], 0, 0, 0);
            }
        }
    }

    float invl = 1.f / lsum;
    #pragma unroll
    for (int r = 0; r < 4; ++r) {
        float ir = __shfl(invl, lg * 4 + r);
        int row = qt0 + w * 16 + lg * 4 + r;
        #pragma unroll
        for (int nt = 0; nt < 4; ++nt)
            Y[(size_t)row * C_DIM + h * HD + nt * 16 + lr] = o[nt][r] * ir;
    }
}

extern "C" void kernel_launch(void* const* d_in, const int* in_sizes, int n_in,
                              void* d_out, int out_size, void* d_ws, size_t ws_size,
                              hipStream_t stream) {
    const float* x      = (const float*)d_in[0];
    const float* w_qkv  = (const float*)d_in[1];
    const float* b_qkv  = (const float*)d_in[2];
    const float* w_proj = (const float*)d_in[3];
    const float* b_proj = (const float*)d_in[4];
    float* out = (float*)d_out;

    float* ws   = (float*)d_ws;
    float* qkv  = ws;                                  // 2048*2304 f32
    float* y    = ws;                                  // reuse (dead after split)
    bf16*  Qh   = (bf16*)(qkv + (size_t)T_SEQ * QKV_N);
    bf16*  Kh   = Qh + (size_t)NH * T_SEQ * HD;
    bf16*  Vh   = Kh + (size_t)NH * T_SEQ * HD;
    float* ctab = (float*)(Vh + (size_t)NH * T_SEQ * HD);
    float* stab = ctab + T_SEQ * 32;

    rope_table_kernel<<<256, 256, 0, stream>>>(ctab, stab);

    dim3 g1(QKV_N / 64, T_SEQ / 64);
    gemm_bias_kernel<<<g1, 256, 0, stream>>>(x, w_qkv, b_qkv, qkv, T_SEQ, QKV_N, C_DIM);

    split_rope_kernel<<<T_SEQ, 256, 0, stream>>>(qkv, ctab, stab, Qh, Kh, Vh);

    dim3 g3(T_SEQ / 64, NH);
    attn_mfma_kernel<<<g3, 256, 0, stream>>>(Qh, Kh, Vh, y);

    dim3 g4(C_DIM / 64, T_SEQ / 64);
    gemm_bias_kernel<<<g4, 256, 0, stream>>>(y, w_proj, b_proj, out, T_SEQ, C_DIM, C_DIM);
}

// Round 3
// 136.160 us; speedup vs baseline: 5.3384x; 1.7108x over previous
//
#include <hip/hip_runtime.h>
#include <hip/hip_bf16.h>
#include <math.h>

#define T_SEQ 2048
#define C_DIM 768
#define NH    12
#define HD    64
#define QKV_N 2304

typedef __attribute__((ext_vector_type(8))) short short8;
typedef __attribute__((ext_vector_type(4))) short short4_t;
typedef __attribute__((ext_vector_type(4))) float f32x4;
typedef __hip_bfloat16 bf16;

static __device__ __forceinline__ unsigned int f2bf(float x) {
    bf16 b = __float2bfloat16(x);
    return (unsigned int)*reinterpret_cast<unsigned short*>(&b);
}

static __device__ __forceinline__ void gload_lds16(const void* g, void* l) {
    __builtin_amdgcn_global_load_lds(
        (const __attribute__((address_space(1))) void*)g,
        (__attribute__((address_space(3))) void*)l, 16, 0, 0);
}

// ---------------- RoPE tables: ctab/stab[t][i], i<32 ----------------
__global__ __launch_bounds__(256) void rope_table_kernel(float* __restrict__ ctab,
                                                         float* __restrict__ stab) {
    int idx = blockIdx.x * 256 + threadIdx.x;
    if (idx >= T_SEQ * 32) return;
    int p = idx >> 5;
    int i = idx & 31;
    float invf = exp2f(-(float)i * (0.03125f * 13.287712379549449f));
    float f = (float)p * invf;
    ctab[idx] = cosf(f);
    stab[idx] = sinf(f);
}

// ---------------- f32 -> bf16 elementwise (n % 1024 == 0) ------------------
__global__ __launch_bounds__(256) void convert_f32_bf16_kernel(
    const float* __restrict__ src, short* __restrict__ dst, int n) {
    int idx = (blockIdx.x * 256 + threadIdx.x) * 4;
    if (idx >= n) return;
    float4 v = *(const float4*)(src + idx);
    short4_t o;
    o[0] = (short)f2bf(v.x); o[1] = (short)f2bf(v.y);
    o[2] = (short)f2bf(v.z); o[3] = (short)f2bf(v.w);
    *(short4_t*)(dst + idx) = o;
}

// ---------------- transpose-convert: W f32 [K][N] -> Wt bf16 [N][K] --------
__global__ __launch_bounds__(256) void transpose_f32_bf16_kernel(
    const float* __restrict__ W, short* __restrict__ Wt, int K, int N) {
    __shared__ float tile[64][65];
    int k0 = blockIdx.y * 64, n0 = blockIdx.x * 64;
    int tid = threadIdx.x;
    #pragma unroll
    for (int e = 0; e < 16; ++e) {
        int idx = e * 256 + tid;
        int r = idx >> 6, c = idx & 63;
        tile[r][c] = W[(size_t)(k0 + r) * N + n0 + c];
    }
    __syncthreads();
    #pragma unroll
    for (int e = 0; e < 16; ++e) {
        int idx = e * 256 + tid;
        int n = idx >> 6, k = idx & 63;
        Wt[(size_t)(n0 + n) * K + k0 + k] = (short)f2bf(tile[k][n]);
    }
}

// ---------------- bf16 MFMA GEMM: C[M][N] = A[M][K] @ Bt[N][K]^T + bias ----
// Block 256 = 4 waves (2x2). Tile 128x128, BK=64.
// LDS layout: [kchunk 0..7][slot-stride 130][8 shorts]; linear dest for
// global_load_lds (lane -> consecutive 16B slots), identity row map.
__global__ __launch_bounds__(256) void gemm_bf16_kernel(
    const short* __restrict__ A, const short* __restrict__ Bt,
    const float* __restrict__ bias, float* __restrict__ C,
    int M, int N, int K) {
    __shared__ __align__(16) short As[8 * 130 * 8];
    __shared__ __align__(16) short Bs[8 * 130 * 8];
    int tid = threadIdx.x;
    int w = tid >> 6, l = tid & 63;
    int lr = l & 15, lg = l >> 4;
    int wm = w >> 1, wn = w & 1;
    int m0 = blockIdx.y * 128, n0 = blockIdx.x * 128;

    f32x4 acc[4][4] = {};

    for (int k0 = 0; k0 < K; k0 += 64) {
        __syncthreads();                       // prev tile consumed
        #pragma unroll
        for (int e = 0; e < 4; ++e) {
            int u = w * 4 + e;                 // 0..15
            int kc = u >> 1, r0 = (u & 1) * 64;
            const short* srcA = A  + (size_t)(m0 + r0 + l) * K + k0 + kc * 8;
            const short* srcB = Bt + (size_t)(n0 + r0 + l) * K + k0 + kc * 8;
            gload_lds16(srcA, &As[(kc * 130 + r0) * 8]);
            gload_lds16(srcB, &Bs[(kc * 130 + r0) * 8]);
        }
        __syncthreads();                       // drains vmcnt(0) + barrier
        #pragma unroll
        for (int ks = 0; ks < 2; ++ks) {
            short8 af[4], bf[4];
            #pragma unroll
            for (int mt = 0; mt < 4; ++mt)
                af[mt] = *(const short8*)&As[((ks * 4 + lg) * 130 + wm * 64 + mt * 16 + lr) * 8];
            #pragma unroll
            for (int nt = 0; nt < 4; ++nt)
                bf[nt] = *(const short8*)&Bs[((ks * 4 + lg) * 130 + wn * 64 + nt * 16 + lr) * 8];
            #pragma unroll
            for (int mt = 0; mt < 4; ++mt)
                #pragma unroll
                for (int nt = 0; nt < 4; ++nt)
                    acc[mt][nt] = __builtin_amdgcn_mfma_f32_16x16x32_bf16(
                        af[mt], bf[nt], acc[mt][nt], 0, 0, 0);
        }
    }

    #pragma unroll
    for (int mt = 0; mt < 4; ++mt)
        #pragma unroll
        for (int r = 0; r < 4; ++r) {
            int row = m0 + wm * 64 + mt * 16 + lg * 4 + r;
            #pragma unroll
            for (int nt = 0; nt < 4; ++nt) {
                int col = n0 + wn * 64 + nt * 16 + lr;
                C[(size_t)row * N + col] = acc[mt][nt][r] + bias[col];
            }
        }
}

// ---------------- split qkv + RoPE -> bf16 head-major Q/K/V [h][t][d] ------
__global__ __launch_bounds__(256) void split_rope_kernel(
    const float* __restrict__ qkv, const float* __restrict__ ctab,
    const float* __restrict__ stab, bf16* __restrict__ Q,
    bf16* __restrict__ K, bf16* __restrict__ V) {
    int t = blockIdx.x;
    int tid = threadIdx.x;
    const float* row = qkv + (size_t)t * QKV_N;
    #pragma unroll
    for (int e = 0; e < 9; ++e) {
        int idx = e * 256 + tid;
        int tensor = idx / 768;
        int hd = idx - tensor * 768;
        int h = hd >> 6;
        int d = hd & 63;
        float v = row[idx];
        size_t dst = ((size_t)h * T_SEQ + t) * HD + d;
        if (tensor == 2) {
            V[dst] = __float2bfloat16(v);
        } else {
            float out;
            if (d < 32) {
                float part = row[idx + 32];
                out = v * ctab[t * 32 + d] - part * stab[t * 32 + d];
            } else {
                int i = d - 32;
                float part = row[idx - 32];
                out = v * ctab[t * 32 + i] + part * stab[t * 32 + i];
            }
            if (tensor == 0) Q[dst] = __float2bfloat16(out * 0.125f);
            else             K[dst] = __float2bfloat16(out);
        }
    }
}

// ---------------- causal flash attention, bf16 MFMA ------------------------
__global__ __launch_bounds__(256) void attn_mfma_kernel(
    const bf16* __restrict__ Qp, const bf16* __restrict__ Kp,
    const bf16* __restrict__ Vp, short* __restrict__ Yb) {
    __shared__ __align__(16) short Ks[64 * 64];
    __shared__ __align__(16) short Vt[64 * 64];
    __shared__ __align__(16) short Pl[4][16 * 64];

    int tid = threadIdx.x;
    int w  = tid >> 6;
    int l  = tid & 63;
    int lr = l & 15;
    int lg = l >> 4;
    int h  = blockIdx.y;
    int qt0 = blockIdx.x * 64;

    const short* Qg = (const short*)(Qp + (size_t)h * T_SEQ * HD);
    const short* Kg = (const short*)(Kp + (size_t)h * T_SEQ * HD);
    const short* Vg = (const short*)(Vp + (size_t)h * T_SEQ * HD);

    int qrow = qt0 + w * 16 + lr;
    short8 qf0 = *(const short8*)(Qg + (size_t)qrow * HD + lg * 8);
    short8 qf1 = *(const short8*)(Qg + (size_t)qrow * HD + 32 + lg * 8);

    f32x4 o[4] = {};
    float m = -INFINITY, lsum = 0.f;
    int nkt = blockIdx.x + 1;

    for (int kt = 0; kt < nkt; ++kt) {
        int k0 = kt * 64;
        __syncthreads();
        {
            int chunk = tid & 7;
            int kv = tid >> 3;
            #pragma unroll
            for (int e = 0; e < 2; ++e) {
                int kkv = kv + e * 32;
                short8 kd = *(const short8*)(Kg + (size_t)(k0 + kkv) * HD + chunk * 8);
                *(short8*)(&Ks[kkv * 64 + ((chunk ^ (kkv & 7)) << 3)]) = kd;
            }
            int kvp = tid >> 3;
            short8 v0 = *(const short8*)(Vg + (size_t)(k0 + 2 * kvp) * HD + chunk * 8);
            short8 v1 = *(const short8*)(Vg + (size_t)(k0 + 2 * kvp + 1) * HD + chunk * 8);
            #pragma unroll
            for (int j = 0; j < 8; ++j) {
                int dim = chunk * 8 + j;
                unsigned int pk = (unsigned int)(unsigned short)v0[j]
                                | ((unsigned int)(unsigned short)v1[j] << 16);
                *(unsigned int*)(&Vt[dim * 64 + (((kvp >> 2) ^ (dim & 7)) << 3)
                                     + (kvp & 3) * 2]) = pk;
            }
        }
        __syncthreads();

        f32x4 c[4];
        #pragma unroll
        for (int mt = 0; mt < 4; ++mt) {
            c[mt] = (f32x4){0.f, 0.f, 0.f, 0.f};
            int row = mt * 16 + lr;
            #pragma unroll
            for (int ks = 0; ks < 2; ++ks) {
                short8 af = *(const short8*)(&Ks[row * 64 + (((ks * 4 + lg) ^ (row & 7)) << 3)]);
                c[mt] = __builtin_amdgcn_mfma_f32_16x16x32_bf16(af, ks ? qf1 : qf0, c[mt], 0, 0, 0);
            }
        }

        int qg = qt0 + w * 16 + lr;
        float p[16];
        float smax = -INFINITY;
        #pragma unroll
        for (int mt = 0; mt < 4; ++mt)
            #pragma unroll
            for (int r = 0; r < 4; ++r) {
                float s = c[mt][r];
                int kvg = k0 + mt * 16 + lg * 4 + r;
                if (kvg > qg) s = -INFINITY;
                p[mt * 4 + r] = s;
                smax = fmaxf(smax, s);
            }
        smax = fmaxf(smax, __shfl_xor(smax, 16));
        smax = fmaxf(smax, __shfl_xor(smax, 32));
        float mnew = fmaxf(m, smax);
        float alpha = __expf(m - mnew);
        float ps = 0.f;
        #pragma unroll
        for (int i = 0; i < 16; ++i) { p[i] = __expf(p[i] - mnew); ps += p[i]; }
        ps += __shfl_xor(ps, 16);
        ps += __shfl_xor(ps, 32);
        lsum = lsum * alpha + ps;
        m = mnew;

        #pragma unroll
        for (int r = 0; r < 4; ++r) {
            float ar = __shfl(alpha, lg * 4 + r);
            #pragma unroll
            for (int nt = 0; nt < 4; ++nt) o[nt][r] *= ar;
        }

        short* Pw = &Pl[w][0];
        #pragma unroll
        for (int mt = 0; mt < 4; ++mt)
            #pragma unroll
            for (int rh = 0; rh < 2; ++rh) {
                unsigned int u = f2bf(p[mt * 4 + 2 * rh]) | (f2bf(p[mt * 4 + 2 * rh + 1]) << 16);
                int chunk = 2 * mt + (lg >> 1);
                *(unsigned int*)(&Pw[lr * 64 + ((chunk ^ (lr & 7)) << 3)
                                     + 4 * (lg & 1) + 2 * rh]) = u;
            }
        asm volatile("" ::: "memory");

        #pragma unroll
        for (int ks = 0; ks < 2; ++ks) {
            short8 pf = *(const short8*)(&Pw[lr * 64 + (((ks * 4 + lg) ^ (lr & 7)) << 3)]);
            #pragma unroll
            for (int nt = 0; nt < 4; ++nt) {
                int vrow = nt * 16 + lr;
                short8 vf = *(const short8*)(&Vt[vrow * 64 + (((ks * 4 + lg) ^ (vrow & 7)) << 3)]);
                o[nt] = __builtin_amdgcn_mfma_f32_16x16x32_bf16(pf, vf, o[nt], 0, 0, 0);
            }
        }
    }

    float invl = 1.f / lsum;
    #pragma unroll
    for (int r = 0; r < 4; ++r) {
        float ir = __shfl(invl, lg * 4 + r);
        int row = qt0 + w * 16 + lg * 4 + r;
        #pragma unroll
        for (int nt = 0; nt < 4; ++nt)
            Yb[(size_t)row * C_DIM + h * HD + nt * 16 + lr] =
                (short)f2bf(o[nt][r] * ir);
    }
}

extern "C" void kernel_launch(void* const* d_in, const int* in_sizes, int n_in,
                              void* d_out, int out_size, void* d_ws, size_t ws_size,
                              hipStream_t stream) {
    const float* x      = (const float*)d_in[0];
    const float* w_qkv  = (const float*)d_in[1];
    const float* b_qkv  = (const float*)d_in[2];
    const float* w_proj = (const float*)d_in[3];
    const float* b_proj = (const float*)d_in[4];
    float* out = (float*)d_out;

    float* ws = (float*)d_ws;
    // region 0: f32 qkv (4,718,592 f). Reused after split: yb, wprojT.
    float* qkv    = ws;
    short* yb     = (short*)ws;                         // 1,572,864 sh
    short* wprojT = (short*)(ws + 786432);              // 589,824 sh
    bf16*  Qh     = (bf16*)(ws + 4718592);              // 1,572,864 sh each
    bf16*  Kh     = Qh + (size_t)NH * T_SEQ * HD;
    bf16*  Vh     = Kh + (size_t)NH * T_SEQ * HD;
    float* ctab   = (float*)(Vh + (size_t)NH * T_SEQ * HD);
    float* stab   = ctab + T_SEQ * 32;
    short* xb     = (short*)(stab + T_SEQ * 32);        // 1,572,864 sh
    short* wqkvT  = xb + (size_t)T_SEQ * C_DIM;         // 1,769,472 sh

    rope_table_kernel<<<256, 256, 0, stream>>>(ctab, stab);

    convert_f32_bf16_kernel<<<(T_SEQ * C_DIM) / 1024, 256, 0, stream>>>(x, xb, T_SEQ * C_DIM);

    dim3 gt1(QKV_N / 64, C_DIM / 64);
    transpose_f32_bf16_kernel<<<gt1, 256, 0, stream>>>(w_qkv, wqkvT, C_DIM, QKV_N);

    dim3 g1(QKV_N / 128, T_SEQ / 128);
    gemm_bf16_kernel<<<g1, 256, 0, stream>>>(xb, wqkvT, b_qkv, qkv, T_SEQ, QKV_N, C_DIM);

    split_rope_kernel<<<T_SEQ, 256, 0, stream>>>(qkv, ctab, stab, Qh, Kh, Vh);

    dim3 gt2(C_DIM / 64, C_DIM / 64);
    transpose_f32_bf16_kernel<<<gt2, 256, 0, stream>>>(w_proj, wprojT, C_DIM, C_DIM);

    dim3 g3(T_SEQ / 64, NH);
    attn_mfma_kernel<<<g3, 256, 0, stream>>>(Qh, Kh, Vh, yb);

    dim3 g4(C_DIM / 128, T_SEQ / 128);
    gemm_bf16_kernel<<<g4, 256, 0, stream>>>(yb, wprojT, b_proj, out, T_SEQ, C_DIM, C_DIM);
}

// Round 4
// 121.929 us; speedup vs baseline: 5.9615x; 1.1167x over previous
//
#include <hip/hip_runtime.h>
#include <hip/hip_bf16.h>
#include <math.h>

#define T_SEQ 2048
#define C_DIM 768
#define NH    12
#define HD    64
#define QKV_N 2304

typedef __attribute__((ext_vector_type(8))) short short8;
typedef __attribute__((ext_vector_type(4))) short short4_t;
typedef __attribute__((ext_vector_type(4))) float f32x4;
typedef __hip_bfloat16 bf16;

static __device__ __forceinline__ unsigned int f2bf(float x) {
    bf16 b = __float2bfloat16(x);
    return (unsigned int)*reinterpret_cast<unsigned short*>(&b);
}

static __device__ __forceinline__ void gload_lds16(const void* g, void* l) {
    __builtin_amdgcn_global_load_lds(
        (const __attribute__((address_space(1))) void*)g,
        (__attribute__((address_space(3))) void*)l, 16, 0, 0);
}

// ---------------- RoPE tables: ctab/stab[t][i], i<32 ----------------
__global__ __launch_bounds__(256) void rope_table_kernel(float* __restrict__ ctab,
                                                         float* __restrict__ stab) {
    int idx = blockIdx.x * 256 + threadIdx.x;
    if (idx >= T_SEQ * 32) return;
    int p = idx >> 5;
    int i = idx & 31;
    float invf = exp2f(-(float)i * (0.03125f * 13.287712379549449f));
    float f = (float)p * invf;
    ctab[idx] = cosf(f);
    stab[idx] = sinf(f);
}

// ---------------- f32 -> bf16 elementwise (n % 1024 == 0) ------------------
__global__ __launch_bounds__(256) void convert_f32_bf16_kernel(
    const float* __restrict__ src, short* __restrict__ dst, int n) {
    int idx = (blockIdx.x * 256 + threadIdx.x) * 4;
    if (idx >= n) return;
    float4 v = *(const float4*)(src + idx);
    short4_t o;
    o[0] = (short)f2bf(v.x); o[1] = (short)f2bf(v.y);
    o[2] = (short)f2bf(v.z); o[3] = (short)f2bf(v.w);
    *(short4_t*)(dst + idx) = o;
}

// ---------------- transpose-convert: W f32 [K][N] -> Wt bf16 [N][K] --------
__global__ __launch_bounds__(256) void transpose_f32_bf16_kernel(
    const float* __restrict__ W, short* __restrict__ Wt, int K, int N) {
    __shared__ float tile[64][65];
    int k0 = blockIdx.y * 64, n0 = blockIdx.x * 64;
    int tid = threadIdx.x;
    #pragma unroll
    for (int e = 0; e < 16; ++e) {
        int idx = e * 256 + tid;
        int r = idx >> 6, c = idx & 63;
        tile[r][c] = W[(size_t)(k0 + r) * N + n0 + c];
    }
    __syncthreads();
    #pragma unroll
    for (int e = 0; e < 16; ++e) {
        int idx = e * 256 + tid;
        int n = idx >> 6, k = idx & 63;
        Wt[(size_t)(n0 + n) * K + k0 + k] = (short)f2bf(tile[k][n]);
    }
}

// ---------------- bf16 MFMA GEMM: C[M][N] = A[M][K] @ Bt[N][K]^T + bias ----
__global__ __launch_bounds__(256) void gemm_bf16_kernel(
    const short* __restrict__ A, const short* __restrict__ Bt,
    const float* __restrict__ bias, float* __restrict__ C,
    int M, int N, int K) {
    __shared__ __align__(16) short As[8 * 130 * 8];
    __shared__ __align__(16) short Bs[8 * 130 * 8];
    int tid = threadIdx.x;
    int w = tid >> 6, l = tid & 63;
    int lr = l & 15, lg = l >> 4;
    int wm = w >> 1, wn = w & 1;
    int m0 = blockIdx.y * 128, n0 = blockIdx.x * 128;

    f32x4 acc[4][4] = {};

    for (int k0 = 0; k0 < K; k0 += 64) {
        __syncthreads();
        #pragma unroll
        for (int e = 0; e < 4; ++e) {
            int u = w * 4 + e;
            int kc = u >> 1, r0 = (u & 1) * 64;
            const short* srcA = A  + (size_t)(m0 + r0 + l) * K + k0 + kc * 8;
            const short* srcB = Bt + (size_t)(n0 + r0 + l) * K + k0 + kc * 8;
            gload_lds16(srcA, &As[(kc * 130 + r0) * 8]);
            gload_lds16(srcB, &Bs[(kc * 130 + r0) * 8]);
        }
        __syncthreads();
        #pragma unroll
        for (int ks = 0; ks < 2; ++ks) {
            short8 af[4], bf[4];
            #pragma unroll
            for (int mt = 0; mt < 4; ++mt)
                af[mt] = *(const short8*)&As[((ks * 4 + lg) * 130 + wm * 64 + mt * 16 + lr) * 8];
            #pragma unroll
            for (int nt = 0; nt < 4; ++nt)
                bf[nt] = *(const short8*)&Bs[((ks * 4 + lg) * 130 + wn * 64 + nt * 16 + lr) * 8];
            #pragma unroll
            for (int mt = 0; mt < 4; ++mt)
                #pragma unroll
                for (int nt = 0; nt < 4; ++nt)
                    acc[mt][nt] = __builtin_amdgcn_mfma_f32_16x16x32_bf16(
                        af[mt], bf[nt], acc[mt][nt], 0, 0, 0);
        }
    }

    #pragma unroll
    for (int mt = 0; mt < 4; ++mt)
        #pragma unroll
        for (int r = 0; r < 4; ++r) {
            int row = m0 + wm * 64 + mt * 16 + lg * 4 + r;
            #pragma unroll
            for (int nt = 0; nt < 4; ++nt) {
                int col = n0 + wn * 64 + nt * 16 + lr;
                C[(size_t)row * N + col] = acc[mt][nt][r] + bias[col];
            }
        }
}

// ---------------- split qkv + RoPE -> bf16 head-major Q/K [h][t][d] --------
// (V handled by v_transpose_kernel.) Q pre-scaled by 1/sqrt(HD).
__global__ __launch_bounds__(256) void split_rope_kernel(
    const float* __restrict__ qkv, const float* __restrict__ ctab,
    const float* __restrict__ stab, bf16* __restrict__ Q,
    bf16* __restrict__ K) {
    int t = blockIdx.x;
    int tid = threadIdx.x;
    const float* row = qkv + (size_t)t * QKV_N;
    #pragma unroll
    for (int e = 0; e < 6; ++e) {
        int idx = e * 256 + tid;               // 0..1535 (Q,K only)
        int tensor = idx / 768;
        int hd = idx - tensor * 768;
        int h = hd >> 6;
        int d = hd & 63;
        float v = row[idx];
        size_t dst = ((size_t)h * T_SEQ + t) * HD + d;
        float out;
        if (d < 32) {
            float part = row[idx + 32];
            out = v * ctab[t * 32 + d] - part * stab[t * 32 + d];
        } else {
            int i = d - 32;
            float part = row[idx - 32];
            out = v * ctab[t * 32 + i] + part * stab[t * 32 + i];
        }
        if (tensor == 0) Q[dst] = __float2bfloat16(out * 0.125f);
        else             K[dst] = __float2bfloat16(out);
    }
}

// ---------------- V global transpose: qkv f32 -> Vt bf16 [h][d][t] ---------
__global__ __launch_bounds__(256) void v_transpose_kernel(
    const float* __restrict__ qkv, short* __restrict__ Vtg) {
    __shared__ float tile[64][65];
    int t0 = blockIdx.x * 64;
    int h  = blockIdx.y;
    int tid = threadIdx.x;
    #pragma unroll
    for (int e = 0; e < 16; ++e) {
        int idx = e * 256 + tid;
        int r = idx >> 6, c = idx & 63;
        tile[r][c] = qkv[(size_t)(t0 + r) * QKV_N + 1536 + h * 64 + c];
    }
    __syncthreads();
    #pragma unroll
    for (int e = 0; e < 16; ++e) {
        int idx = e * 256 + tid;
        int d = idx >> 6, tt = idx & 63;
        Vtg[((size_t)h * HD + d) * T_SEQ + t0 + tt] = (short)f2bf(tile[tt][d]);
    }
}

// ---------------- causal flash attention, bf16 MFMA, double-buffered -------
// 1-D grid of 384 jobs, LPT order (longest q-tiles first).
// Per tile: stage(next) via global_load_lds -> s_waitcnt vmcnt(4) -> barrier
// -> QK^T + softmax + PV -> barrier. No vmcnt(0) drain mid-loop (T3/T4).
__global__ __launch_bounds__(256) void attn_mfma_kernel(
    const bf16* __restrict__ Qp, const bf16* __restrict__ Kp,
    const bf16* __restrict__ Vtp, short* __restrict__ Yb) {
    __shared__ __align__(16) short KsB[2][64 * 64];  // [kv][d], chunk^row swizzle
    __shared__ __align__(16) short VtB[2][64 * 64];  // [d][kv], chunk^row swizzle
    __shared__ __align__(16) short Pl[4][16 * 64];   // per-wave P [q][kv]

    int tid = threadIdx.x;
    int w  = tid >> 6;
    int l  = tid & 63;
    int lr = l & 15;
    int lg = l >> 4;

    int job = blockIdx.x;            // LPT: qi=31 (32 tiles) dispatched first
    int qi  = 31 - job / NH;
    int h   = job % NH;
    int qt0 = qi * 64;
    int nkt = qi + 1;

    const short* Qg  = (const short*)(Qp + (size_t)h * T_SEQ * HD);
    const short* Kg  = (const short*)(Kp + (size_t)h * T_SEQ * HD);
    const short* Vtg = (const short*)(Vtp + (size_t)h * HD * T_SEQ);

    int qrow = qt0 + w * 16 + lr;
    short8 qf0 = *(const short8*)(Qg + (size_t)qrow * HD + lg * 8);
    short8 qf1 = *(const short8*)(Qg + (size_t)qrow * HD + 32 + lg * 8);

    int srow = l >> 3;              // 0..7: row within 8-row staging group
    int cx   = (l & 7) ^ srow;      // inverse-swizzled source chunk (rule #21)

    auto stage = [&](int buf, int kt) {
        int k0 = kt * 64;
        #pragma unroll
        for (int e = 0; e < 2; ++e) {
            int r = e * 32 + w * 8 + srow;
            gload_lds16(Kg + (size_t)(k0 + r) * HD + cx * 8,
                        &KsB[buf][(e * 256 + w * 64) * 8]);
            gload_lds16(Vtg + (size_t)r * T_SEQ + k0 + cx * 8,
                        &VtB[buf][(e * 256 + w * 64) * 8]);
        }
    };

    f32x4 o[4] = {};
    float m = -INFINITY, lsum = 0.f;

    stage(0, 0);

    for (int kt = 0; kt < nkt; ++kt) {
        int cur = kt & 1;
        if (kt + 1 < nkt) {
            stage(1 - cur, kt + 1);                       // prefetch next tile
            asm volatile("s_waitcnt vmcnt(4)" ::: "memory");  // cur ready, next in flight
        } else {
            asm volatile("s_waitcnt vmcnt(0)" ::: "memory");
        }
        __builtin_amdgcn_s_barrier();

        const short* Ks = KsB[cur];
        const short* Vt = VtB[cur];

        // QK^T (swapped): lane holds S[q=lr][16 kv values]
        f32x4 c[4];
        #pragma unroll
        for (int mt = 0; mt < 4; ++mt) {
            c[mt] = (f32x4){0.f, 0.f, 0.f, 0.f};
            int row = mt * 16 + lr;
            #pragma unroll
            for (int ks = 0; ks < 2; ++ks) {
                short8 af = *(const short8*)(&Ks[row * 64 + (((ks * 4 + lg) ^ (row & 7)) << 3)]);
                c[mt] = __builtin_amdgcn_mfma_f32_16x16x32_bf16(af, ks ? qf1 : qf0, c[mt], 0, 0, 0);
            }
        }

        // online softmax; mask only the diagonal tile
        float p[16];
        float smax = -INFINITY;
        if (kt == nkt - 1) {
            int qg = qt0 + w * 16 + lr;
            int k0 = kt * 64;
            #pragma unroll
            for (int mt = 0; mt < 4; ++mt)
                #pragma unroll
                for (int r = 0; r < 4; ++r) {
                    float s = c[mt][r];
                    if (k0 + mt * 16 + lg * 4 + r > qg) s = -INFINITY;
                    p[mt * 4 + r] = s;
                    smax = fmaxf(smax, s);
                }
        } else {
            #pragma unroll
            for (int mt = 0; mt < 4; ++mt)
                #pragma unroll
                for (int r = 0; r < 4; ++r) {
                    float s = c[mt][r];
                    p[mt * 4 + r] = s;
                    smax = fmaxf(smax, s);
                }
        }
        smax = fmaxf(smax, __shfl_xor(smax, 16));
        smax = fmaxf(smax, __shfl_xor(smax, 32));
        float mnew = fmaxf(m, smax);
        float alpha = __expf(m - mnew);
        float ps = 0.f;
        #pragma unroll
        for (int i = 0; i < 16; ++i) { p[i] = __expf(p[i] - mnew); ps += p[i]; }
        ps += __shfl_xor(ps, 16);
        ps += __shfl_xor(ps, 32);
        lsum = lsum * alpha + ps;
        m = mnew;

        #pragma unroll
        for (int r = 0; r < 4; ++r) {
            float ar = __shfl(alpha, lg * 4 + r);
            #pragma unroll
            for (int nt = 0; nt < 4; ++nt) o[nt][r] *= ar;
        }

        // P -> per-wave LDS (A-frag layout), then PV
        short* Pw = &Pl[w][0];
        #pragma unroll
        for (int mt = 0; mt < 4; ++mt)
            #pragma unroll
            for (int rh = 0; rh < 2; ++rh) {
                unsigned int u = f2bf(p[mt * 4 + 2 * rh]) | (f2bf(p[mt * 4 + 2 * rh + 1]) << 16);
                int chunk = 2 * mt + (lg >> 1);
                *(unsigned int*)(&Pw[lr * 64 + ((chunk ^ (lr & 7)) << 3)
                                     + 4 * (lg & 1) + 2 * rh]) = u;
            }
        asm volatile("" ::: "memory");

        #pragma unroll
        for (int ks = 0; ks < 2; ++ks) {
            short8 pf = *(const short8*)(&Pw[lr * 64 + (((ks * 4 + lg) ^ (lr & 7)) << 3)]);
            #pragma unroll
            for (int nt = 0; nt < 4; ++nt) {
                int vrow = nt * 16 + lr;
                short8 vf = *(const short8*)(&Vt[vrow * 64 + (((ks * 4 + lg) ^ (vrow & 7)) << 3)]);
                o[nt] = __builtin_amdgcn_mfma_f32_16x16x32_bf16(pf, vf, o[nt], 0, 0, 0);
            }
        }
        __builtin_amdgcn_s_barrier();   // cur consumed; safe to overwrite next iter
    }

    float invl = 1.f / lsum;
    #pragma unroll
    for (int r = 0; r < 4; ++r) {
        float ir = __shfl(invl, lg * 4 + r);
        int row = qt0 + w * 16 + lg * 4 + r;
        #pragma unroll
        for (int nt = 0; nt < 4; ++nt)
            Yb[(size_t)row * C_DIM + h * HD + nt * 16 + lr] =
                (short)f2bf(o[nt][r] * ir);
    }
}

extern "C" void kernel_launch(void* const* d_in, const int* in_sizes, int n_in,
                              void* d_out, int out_size, void* d_ws, size_t ws_size,
                              hipStream_t stream) {
    const float* x      = (const float*)d_in[0];
    const float* w_qkv  = (const float*)d_in[1];
    const float* b_qkv  = (const float*)d_in[2];
    const float* w_proj = (const float*)d_in[3];
    const float* b_proj = (const float*)d_in[4];
    float* out = (float*)d_out;

    float* ws = (float*)d_ws;
    // region 0: f32 qkv (4,718,592 f). Reused after split+vt: yb, wprojT.
    float* qkv    = ws;
    short* yb     = (short*)ws;                         // 1,572,864 sh
    short* wprojT = (short*)(ws + 786432);              // 589,824 sh
    bf16*  Qh     = (bf16*)(ws + 4718592);              // 1,572,864 sh each
    bf16*  Kh     = Qh + (size_t)NH * T_SEQ * HD;
    bf16*  Vt     = Kh + (size_t)NH * T_SEQ * HD;       // [h][d][t]
    float* ctab   = (float*)(Vt + (size_t)NH * T_SEQ * HD);
    float* stab   = ctab + T_SEQ * 32;
    short* xb     = (short*)(stab + T_SEQ * 32);        // 1,572,864 sh
    short* wqkvT  = xb + (size_t)T_SEQ * C_DIM;         // 1,769,472 sh

    rope_table_kernel<<<256, 256, 0, stream>>>(ctab, stab);

    convert_f32_bf16_kernel<<<(T_SEQ * C_DIM) / 1024, 256, 0, stream>>>(x, xb, T_SEQ * C_DIM);

    dim3 gt1(QKV_N / 64, C_DIM / 64);
    transpose_f32_bf16_kernel<<<gt1, 256, 0, stream>>>(w_qkv, wqkvT, C_DIM, QKV_N);

    dim3 g1(QKV_N / 128, T_SEQ / 128);
    gemm_bf16_kernel<<<g1, 256, 0, stream>>>(xb, wqkvT, b_qkv, qkv, T_SEQ, QKV_N, C_DIM);

    split_rope_kernel<<<T_SEQ, 256, 0, stream>>>(qkv, ctab, stab, Qh, Kh);

    dim3 gv(T_SEQ / 64, NH);
    v_transpose_kernel<<<gv, 256, 0, stream>>>(qkv, (short*)Vt);

    // wprojT overlaps the f32 qkv region -> must come after split_rope + v_transpose
    dim3 gt2(C_DIM / 64, C_DIM / 64);
    transpose_f32_bf16_kernel<<<gt2, 256, 0, stream>>>(w_proj, wprojT, C_DIM, C_DIM);

    attn_mfma_kernel<<<NH * 32, 256, 0, stream>>>(Qh, Kh, Vt, yb);

    dim3 g4(C_DIM / 128, T_SEQ / 128);
    gemm_bf16_kernel<<<g4, 256, 0, stream>>>(yb, wprojT, b_proj, out, T_SEQ, C_DIM, C_DIM);
}

// Round 5
// 109.874 us; speedup vs baseline: 6.6155x; 1.1097x over previous
//
#include <hip/hip_runtime.h>
#include <hip/hip_bf16.h>
#include <math.h>

#define T_SEQ 2048
#define C_DIM 768
#define NH    12
#define HD    64
#define QKV_N 2304
#define CH    8          // kv-tiles per attention chunk (split-K)
#define NJOBS 960        // 12 heads x 80 (qi,chunk) pairs

typedef __attribute__((ext_vector_type(8))) short short8;
typedef __attribute__((ext_vector_type(4))) short short4_t;
typedef __attribute__((ext_vector_type(4))) float f32x4;
typedef __hip_bfloat16 bf16;

static __device__ __forceinline__ unsigned int f2bf(float x) {
    bf16 b = __float2bfloat16(x);
    return (unsigned int)*reinterpret_cast<unsigned short*>(&b);
}
static __device__ __forceinline__ float bf2f(short u) {
    unsigned int v = ((unsigned int)(unsigned short)u) << 16;
    return *reinterpret_cast<float*>(&v);
}

static __device__ __forceinline__ void gload_lds16(const void* g, void* l) {
    __builtin_amdgcn_global_load_lds(
        (const __attribute__((address_space(1))) void*)g,
        (__attribute__((address_space(3))) void*)l, 16, 0, 0);
}

// ---------------- RoPE tables: ctab/stab[t][i], i<32 ----------------
__global__ __launch_bounds__(256) void rope_table_kernel(float* __restrict__ ctab,
                                                         float* __restrict__ stab) {
    int idx = blockIdx.x * 256 + threadIdx.x;
    if (idx >= T_SEQ * 32) return;
    int p = idx >> 5;
    int i = idx & 31;
    float invf = exp2f(-(float)i * (0.03125f * 13.287712379549449f));
    float f = (float)p * invf;
    ctab[idx] = cosf(f);
    stab[idx] = sinf(f);
}

// ---------------- f32 -> bf16 elementwise (n % 1024 == 0) ------------------
__global__ __launch_bounds__(256) void convert_f32_bf16_kernel(
    const float* __restrict__ src, short* __restrict__ dst, int n) {
    int idx = (blockIdx.x * 256 + threadIdx.x) * 4;
    if (idx >= n) return;
    float4 v = *(const float4*)(src + idx);
    short4_t o;
    o[0] = (short)f2bf(v.x); o[1] = (short)f2bf(v.y);
    o[2] = (short)f2bf(v.z); o[3] = (short)f2bf(v.w);
    *(short4_t*)(dst + idx) = o;
}

// ---------------- transpose-convert: W f32 [K][N] -> Wt bf16 [N][K] --------
__global__ __launch_bounds__(256) void transpose_f32_bf16_kernel(
    const float* __restrict__ W, short* __restrict__ Wt, int K, int N) {
    __shared__ float tile[64][65];
    int k0 = blockIdx.y * 64, n0 = blockIdx.x * 64;
    int tid = threadIdx.x;
    #pragma unroll
    for (int e = 0; e < 16; ++e) {
        int idx = e * 256 + tid;
        int r = idx >> 6, c = idx & 63;
        tile[r][c] = W[(size_t)(k0 + r) * N + n0 + c];
    }
    __syncthreads();
    #pragma unroll
    for (int e = 0; e < 16; ++e) {
        int idx = e * 256 + tid;
        int n = idx >> 6, k = idx & 63;
        Wt[(size_t)(n0 + n) * K + k0 + k] = (short)f2bf(tile[k][n]);
    }
}

// ---------------- bf16 MFMA GEMM: C[M][N] = A[M][K] @ Bt[N][K]^T + bias ----
__global__ __launch_bounds__(256) void gemm_bf16_kernel(
    const short* __restrict__ A, const short* __restrict__ Bt,
    const float* __restrict__ bias, float* __restrict__ C,
    int M, int N, int K) {
    __shared__ __align__(16) short As[8 * 130 * 8];
    __shared__ __align__(16) short Bs[8 * 130 * 8];
    int tid = threadIdx.x;
    int w = tid >> 6, l = tid & 63;
    int lr = l & 15, lg = l >> 4;
    int wm = w >> 1, wn = w & 1;
    int m0 = blockIdx.y * 128, n0 = blockIdx.x * 128;

    f32x4 acc[4][4] = {};

    for (int k0 = 0; k0 < K; k0 += 64) {
        __syncthreads();
        #pragma unroll
        for (int e = 0; e < 4; ++e) {
            int u = w * 4 + e;
            int kc = u >> 1, r0 = (u & 1) * 64;
            const short* srcA = A  + (size_t)(m0 + r0 + l) * K + k0 + kc * 8;
            const short* srcB = Bt + (size_t)(n0 + r0 + l) * K + k0 + kc * 8;
            gload_lds16(srcA, &As[(kc * 130 + r0) * 8]);
            gload_lds16(srcB, &Bs[(kc * 130 + r0) * 8]);
        }
        __syncthreads();
        #pragma unroll
        for (int ks = 0; ks < 2; ++ks) {
            short8 af[4], bf[4];
            #pragma unroll
            for (int mt = 0; mt < 4; ++mt)
                af[mt] = *(const short8*)&As[((ks * 4 + lg) * 130 + wm * 64 + mt * 16 + lr) * 8];
            #pragma unroll
            for (int nt = 0; nt < 4; ++nt)
                bf[nt] = *(const short8*)&Bs[((ks * 4 + lg) * 130 + wn * 64 + nt * 16 + lr) * 8];
            #pragma unroll
            for (int mt = 0; mt < 4; ++mt)
                #pragma unroll
                for (int nt = 0; nt < 4; ++nt)
                    acc[mt][nt] = __builtin_amdgcn_mfma_f32_16x16x32_bf16(
                        af[mt], bf[nt], acc[mt][nt], 0, 0, 0);
        }
    }

    #pragma unroll
    for (int mt = 0; mt < 4; ++mt)
        #pragma unroll
        for (int r = 0; r < 4; ++r) {
            int row = m0 + wm * 64 + mt * 16 + lg * 4 + r;
            #pragma unroll
            for (int nt = 0; nt < 4; ++nt) {
                int col = n0 + wn * 64 + nt * 16 + lr;
                C[(size_t)row * N + col] = acc[mt][nt][r] + bias[col];
            }
        }
}

// ---------------- split qkv + RoPE -> bf16 head-major Q/K [h][t][d] --------
__global__ __launch_bounds__(256) void split_rope_kernel(
    const float* __restrict__ qkv, const float* __restrict__ ctab,
    const float* __restrict__ stab, bf16* __restrict__ Q,
    bf16* __restrict__ K) {
    int t = blockIdx.x;
    int tid = threadIdx.x;
    const float* row = qkv + (size_t)t * QKV_N;
    #pragma unroll
    for (int e = 0; e < 6; ++e) {
        int idx = e * 256 + tid;               // 0..1535 (Q,K only)
        int tensor = idx / 768;
        int hd = idx - tensor * 768;
        int h = hd >> 6;
        int d = hd & 63;
        float v = row[idx];
        size_t dst = ((size_t)h * T_SEQ + t) * HD + d;
        float out;
        if (d < 32) {
            float part = row[idx + 32];
            out = v * ctab[t * 32 + d] - part * stab[t * 32 + d];
        } else {
            int i = d - 32;
            float part = row[idx - 32];
            out = v * ctab[t * 32 + i] + part * stab[t * 32 + i];
        }
        if (tensor == 0) Q[dst] = __float2bfloat16(out * 0.125f);
        else             K[dst] = __float2bfloat16(out);
    }
}

// ---------------- V global transpose: qkv f32 -> Vt bf16 [h][d][t] ---------
__global__ __launch_bounds__(256) void v_transpose_kernel(
    const float* __restrict__ qkv, short* __restrict__ Vtg) {
    __shared__ float tile[64][65];
    int t0 = blockIdx.x * 64;
    int h  = blockIdx.y;
    int tid = threadIdx.x;
    #pragma unroll
    for (int e = 0; e < 16; ++e) {
        int idx = e * 256 + tid;
        int r = idx >> 6, c = idx & 63;
        tile[r][c] = qkv[(size_t)(t0 + r) * QKV_N + 1536 + h * 64 + c];
    }
    __syncthreads();
    #pragma unroll
    for (int e = 0; e < 16; ++e) {
        int idx = e * 256 + tid;
        int d = idx >> 6, tt = idx & 63;
        Vtg[((size_t)h * HD + d) * T_SEQ + t0 + tt] = (short)f2bf(tile[tt][d]);
    }
}

// ---------------- causal flash attention, bf16 MFMA, split-K ---------------
// 960 jobs = 12 heads x {(qi, chunk)}: qi 0..7 -> 1 chunk, 8..15 -> 2,
// 16..23 -> 3, 24..31 -> 4 (CH=8 kv-tiles per chunk).
// Single-chunk jobs write final Yb; others write unnormalized O + (m,l).
__global__ __launch_bounds__(256) void attn_mfma_kernel(
    const bf16* __restrict__ Qp, const bf16* __restrict__ Kp,
    const bf16* __restrict__ Vtp, short* __restrict__ Yb,
    short* __restrict__ Opart, float* __restrict__ ml) {
    __shared__ __align__(16) short KsB[2][64 * 64];
    __shared__ __align__(16) short VtB[2][64 * 64];
    __shared__ __align__(16) short Pl[4][16 * 64];

    int tid = threadIdx.x;
    int w  = tid >> 6;
    int l  = tid & 63;
    int lr = l & 15;
    int lg = l >> 4;

    int job = (NJOBS - 1) - blockIdx.x;   // long-qi chunks dispatch first
    int h = job % NH;
    int u = job / NH;                     // 0..79
    int qi, c0;
    if (u < 8)       { qi = u;                      c0 = 0; }
    else if (u < 24) { int v = u - 8;  qi = 8  + (v >> 1); c0 = v & 1; }
    else if (u < 48) { int v = u - 24; qi = 16 + v / 3;    c0 = v - (v / 3) * 3; }
    else             { int v = u - 48; qi = 24 + (v >> 2); c0 = v & 3; }
    int kt0 = c0 * CH;
    int kt1 = kt0 + CH; if (kt1 > qi + 1) kt1 = qi + 1;
    int nch = (qi + CH) >> 3;             // ceil((qi+1)/8)
    int qt0 = qi * 64;

    const short* Qg  = (const short*)(Qp + (size_t)h * T_SEQ * HD);
    const short* Kg  = (const short*)(Kp + (size_t)h * T_SEQ * HD);
    const short* Vtg = (const short*)(Vtp + (size_t)h * HD * T_SEQ);

    int qrow = qt0 + w * 16 + lr;
    short8 qf0 = *(const short8*)(Qg + (size_t)qrow * HD + lg * 8);
    short8 qf1 = *(const short8*)(Qg + (size_t)qrow * HD + 32 + lg * 8);

    int srow = l >> 3;
    int cx   = (l & 7) ^ srow;            // inverse-swizzled source chunk

    auto stage = [&](int buf, int kt) {
        int k0 = kt * 64;
        #pragma unroll
        for (int e = 0; e < 2; ++e) {
            int r = e * 32 + w * 8 + srow;
            gload_lds16(Kg + (size_t)(k0 + r) * HD + cx * 8,
                        &KsB[buf][(e * 256 + w * 64) * 8]);
            gload_lds16(Vtg + (size_t)r * T_SEQ + k0 + cx * 8,
                        &VtB[buf][(e * 256 + w * 64) * 8]);
        }
    };

    f32x4 o[4] = {};
    float m = -INFINITY, lsum = 0.f;

    stage(0, kt0);

    for (int kt = kt0; kt < kt1; ++kt) {
        int cur = (kt - kt0) & 1;
        if (kt + 1 < kt1) {
            stage(1 - cur, kt + 1);
            asm volatile("s_waitcnt vmcnt(4)" ::: "memory");
        } else {
            asm volatile("s_waitcnt vmcnt(0)" ::: "memory");
        }
        __builtin_amdgcn_s_barrier();

        const short* Ks = KsB[cur];
        const short* Vt = VtB[cur];

        f32x4 c[4];
        #pragma unroll
        for (int mt = 0; mt < 4; ++mt) {
            c[mt] = (f32x4){0.f, 0.f, 0.f, 0.f};
            int row = mt * 16 + lr;
            #pragma unroll
            for (int ks = 0; ks < 2; ++ks) {
                short8 af = *(const short8*)(&Ks[row * 64 + (((ks * 4 + lg) ^ (row & 7)) << 3)]);
                c[mt] = __builtin_amdgcn_mfma_f32_16x16x32_bf16(af, ks ? qf1 : qf0, c[mt], 0, 0, 0);
            }
        }

        float p[16];
        float smax = -INFINITY;
        if (kt == qi) {                    // diagonal tile: causal mask
            int qg = qt0 + w * 16 + lr;
            int k0 = kt * 64;
            #pragma unroll
            for (int mt = 0; mt < 4; ++mt)
                #pragma unroll
                for (int r = 0; r < 4; ++r) {
                    float s = c[mt][r];
                    if (k0 + mt * 16 + lg * 4 + r > qg) s = -INFINITY;
                    p[mt * 4 + r] = s;
                    smax = fmaxf(smax, s);
                }
        } else {
            #pragma unroll
            for (int mt = 0; mt < 4; ++mt)
                #pragma unroll
                for (int r = 0; r < 4; ++r) {
                    float s = c[mt][r];
                    p[mt * 4 + r] = s;
                    smax = fmaxf(smax, s);
                }
        }
        smax = fmaxf(smax, __shfl_xor(smax, 16));
        smax = fmaxf(smax, __shfl_xor(smax, 32));
        float mnew = fmaxf(m, smax);
        float alpha = __expf(m - mnew);
        float ps = 0.f;
        #pragma unroll
        for (int i = 0; i < 16; ++i) { p[i] = __expf(p[i] - mnew); ps += p[i]; }
        ps += __shfl_xor(ps, 16);
        ps += __shfl_xor(ps, 32);
        lsum = lsum * alpha + ps;
        m = mnew;

        #pragma unroll
        for (int r = 0; r < 4; ++r) {
            float ar = __shfl(alpha, lg * 4 + r);
            #pragma unroll
            for (int nt = 0; nt < 4; ++nt) o[nt][r] *= ar;
        }

        short* Pw = &Pl[w][0];
        #pragma unroll
        for (int mt = 0; mt < 4; ++mt)
            #pragma unroll
            for (int rh = 0; rh < 2; ++rh) {
                unsigned int uu = f2bf(p[mt * 4 + 2 * rh]) | (f2bf(p[mt * 4 + 2 * rh + 1]) << 16);
                int chunk = 2 * mt + (lg >> 1);
                *(unsigned int*)(&Pw[lr * 64 + ((chunk ^ (lr & 7)) << 3)
                                     + 4 * (lg & 1) + 2 * rh]) = uu;
            }
        asm volatile("" ::: "memory");

        #pragma unroll
        for (int ks = 0; ks < 2; ++ks) {
            short8 pf = *(const short8*)(&Pw[lr * 64 + (((ks * 4 + lg) ^ (lr & 7)) << 3)]);
            #pragma unroll
            for (int nt = 0; nt < 4; ++nt) {
                int vrow = nt * 16 + lr;
                short8 vf = *(const short8*)(&Vt[vrow * 64 + (((ks * 4 + lg) ^ (vrow & 7)) << 3)]);
                o[nt] = __builtin_amdgcn_mfma_f32_16x16x32_bf16(pf, vf, o[nt], 0, 0, 0);
            }
        }
        __builtin_amdgcn_s_barrier();
    }

    if (nch == 1) {
        float invl = 1.f / lsum;
        #pragma unroll
        for (int r = 0; r < 4; ++r) {
            float ir = __shfl(invl, lg * 4 + r);
            int row = qt0 + w * 16 + lg * 4 + r;
            #pragma unroll
            for (int nt = 0; nt < 4; ++nt)
                Yb[(size_t)row * C_DIM + h * HD + nt * 16 + lr] =
                    (short)f2bf(o[nt][r] * ir);
        }
    } else {
        if (lg == 0) {
            ml[(size_t)job * 128 + w * 16 + lr] = m;
            ml[(size_t)job * 128 + 64 + w * 16 + lr] = lsum;
        }
        #pragma unroll
        for (int r = 0; r < 4; ++r) {
            int row = w * 16 + lg * 4 + r;
            #pragma unroll
            for (int nt = 0; nt < 4; ++nt)
                Opart[(size_t)job * 4096 + row * 64 + nt * 16 + lr] =
                    (short)f2bf(o[nt][r]);
        }
    }
}

// ---------------- combine split-K partials (qi >= 8) -----------------------
// 288 blocks = 12 heads x 24 qi. Thread: row = tid>>2, dim quarter = tid&3.
__global__ __launch_bounds__(256) void combine_kernel(
    const short* __restrict__ Opart, const float* __restrict__ ml,
    short* __restrict__ Yb) {
    int job = blockIdx.x;
    int h  = job % NH;
    int qi = 8 + job / NH;
    int nch = (qi + CH) >> 3;
    int u0;
    if (qi < 16)      u0 = 8  + (qi - 8) * 2;
    else if (qi < 24) u0 = 24 + (qi - 16) * 3;
    else              u0 = 48 + (qi - 24) * 4;

    int tid = threadIdx.x;
    int row = tid >> 2;
    int qp  = tid & 3;

    float mm[4], ll[4];
    float M = -INFINITY;
    #pragma unroll
    for (int c = 0; c < 4; ++c) {
        mm[c] = -INFINITY; ll[c] = 0.f;
        if (c < nch) {
            size_t pidx = (size_t)(u0 + c) * NH + h;
            mm[c] = ml[pidx * 128 + row];
            ll[c] = ml[pidx * 128 + 64 + row];
            M = fmaxf(M, mm[c]);
        }
    }
    float acc[16] = {};
    float L = 0.f;
    #pragma unroll
    for (int c = 0; c < 4; ++c) {
        if (c < nch) {
            float wgt = __expf(mm[c] - M);
            L += ll[c] * wgt;
            const short* op = Opart + ((size_t)(u0 + c) * NH + h) * 4096
                            + row * 64 + qp * 16;
            short8 a = *(const short8*)op;
            short8 b = *(const short8*)(op + 8);
            #pragma unroll
            for (int j = 0; j < 8; ++j) {
                acc[j]     += wgt * bf2f(a[j]);
                acc[8 + j] += wgt * bf2f(b[j]);
            }
        }
    }
    float invL = 1.f / L;
    short8 oa, ob;
    #pragma unroll
    for (int j = 0; j < 8; ++j) {
        oa[j] = (short)f2bf(acc[j] * invL);
        ob[j] = (short)f2bf(acc[8 + j] * invL);
    }
    short* dst = Yb + (size_t)(qi * 64 + row) * C_DIM + h * HD + qp * 16;
    *(short8*)dst = oa;
    *(short8*)(dst + 8) = ob;
}

extern "C" void kernel_launch(void* const* d_in, const int* in_sizes, int n_in,
                              void* d_out, int out_size, void* d_ws, size_t ws_size,
                              hipStream_t stream) {
    const float* x      = (const float*)d_in[0];
    const float* w_qkv  = (const float*)d_in[1];
    const float* b_qkv  = (const float*)d_in[2];
    const float* w_proj = (const float*)d_in[3];
    const float* b_proj = (const float*)d_in[4];
    float* out = (float*)d_out;

    float* ws = (float*)d_ws;
    // region 0: f32 qkv (4,718,592 f), dead after split_rope + v_transpose.
    // Reused as: yb | wprojT | Opart | ml  (total 3,170,304 f -- fits).
    float* qkv    = ws;
    short* yb     = (short*)ws;                          // 1,572,864 sh
    short* wprojT = (short*)(ws + 786432);               // 589,824 sh
    short* Opart  = (short*)(ws + 1081344);              // 960*4096 sh
    float* mlbuf  = ws + 3047424;                        // 960*128 f
    bf16*  Qh     = (bf16*)(ws + 4718592);
    bf16*  Kh     = Qh + (size_t)NH * T_SEQ * HD;
    bf16*  Vt     = Kh + (size_t)NH * T_SEQ * HD;        // [h][d][t]
    float* ctab   = (float*)(Vt + (size_t)NH * T_SEQ * HD);
    float* stab   = ctab + T_SEQ * 32;
    short* xb     = (short*)(stab + T_SEQ * 32);
    short* wqkvT  = xb + (size_t)T_SEQ * C_DIM;

    rope_table_kernel<<<256, 256, 0, stream>>>(ctab, stab);

    convert_f32_bf16_kernel<<<(T_SEQ * C_DIM) / 1024, 256, 0, stream>>>(x, xb, T_SEQ * C_DIM);

    dim3 gt1(QKV_N / 64, C_DIM / 64);
    transpose_f32_bf16_kernel<<<gt1, 256, 0, stream>>>(w_qkv, wqkvT, C_DIM, QKV_N);

    dim3 g1(QKV_N / 128, T_SEQ / 128);
    gemm_bf16_kernel<<<g1, 256, 0, stream>>>(xb, wqkvT, b_qkv, qkv, T_SEQ, QKV_N, C_DIM);

    split_rope_kernel<<<T_SEQ, 256, 0, stream>>>(qkv, ctab, stab, Qh, Kh);

    dim3 gv(T_SEQ / 64, NH);
    v_transpose_kernel<<<gv, 256, 0, stream>>>(qkv, (short*)Vt);

    // wprojT/partials overlap the f32 qkv region -> after split_rope + v_transpose
    dim3 gt2(C_DIM / 64, C_DIM / 64);
    transpose_f32_bf16_kernel<<<gt2, 256, 0, stream>>>(w_proj, wprojT, C_DIM, C_DIM);

    attn_mfma_kernel<<<NJOBS, 256, 0, stream>>>(Qh, Kh, Vt, yb, Opart, mlbuf);

    combine_kernel<<<NH * 24, 256, 0, stream>>>(Opart, mlbuf, yb);

    dim3 g4(C_DIM / 128, T_SEQ / 128);
    gemm_bf16_kernel<<<g4, 256, 0, stream>>>(yb, wprojT, b_proj, out, T_SEQ, C_DIM, C_DIM);
}

// Round 6
// 99.706 us; speedup vs baseline: 7.2902x; 1.1020x over previous
//
#include <hip/hip_runtime.h>
#include <hip/hip_bf16.h>
#include <math.h>

#define T_SEQ 2048
#define C_DIM 768
#define NH    12
#define HD    64
#define QKV_N 2304
#define CH    8          // kv-tiles per attention chunk (split-K)
#define NJOBS 960        // 12 heads x 80 (qi,chunk) pairs

typedef __attribute__((ext_vector_type(8))) short short8;
typedef __attribute__((ext_vector_type(4))) short short4_t;
typedef __attribute__((ext_vector_type(4))) float f32x4;
typedef __hip_bfloat16 bf16;

static __device__ __forceinline__ unsigned int f2bf(float x) {
    bf16 b = __float2bfloat16(x);
    return (unsigned int)*reinterpret_cast<unsigned short*>(&b);
}
static __device__ __forceinline__ float bf2f(short u) {
    unsigned int v = ((unsigned int)(unsigned short)u) << 16;
    return *reinterpret_cast<float*>(&v);
}

static __device__ __forceinline__ void gload_lds16(const void* g, void* l) {
    __builtin_amdgcn_global_load_lds(
        (const __attribute__((address_space(1))) void*)g,
        (__attribute__((address_space(3))) void*)l, 16, 0, 0);
}

// ---------------- RoPE tables: ctab/stab[t][i], i<32 ----------------
__global__ __launch_bounds__(256) void rope_table_kernel(float* __restrict__ ctab,
                                                         float* __restrict__ stab) {
    int idx = blockIdx.x * 256 + threadIdx.x;
    if (idx >= T_SEQ * 32) return;
    int p = idx >> 5;
    int i = idx & 31;
    float invf = exp2f(-(float)i * (0.03125f * 13.287712379549449f));
    float f = (float)p * invf;
    ctab[idx] = cosf(f);
    stab[idx] = sinf(f);
}

// ---------------- f32 -> bf16 elementwise (n % 1024 == 0) ------------------
__global__ __launch_bounds__(256) void convert_f32_bf16_kernel(
    const float* __restrict__ src, short* __restrict__ dst, int n) {
    int idx = (blockIdx.x * 256 + threadIdx.x) * 4;
    if (idx >= n) return;
    float4 v = *(const float4*)(src + idx);
    short4_t o;
    o[0] = (short)f2bf(v.x); o[1] = (short)f2bf(v.y);
    o[2] = (short)f2bf(v.z); o[3] = (short)f2bf(v.w);
    *(short4_t*)(dst + idx) = o;
}

// ---------------- transpose-convert: W f32 [K][N] -> Wt bf16 [N][K] --------
__global__ __launch_bounds__(256) void transpose_f32_bf16_kernel(
    const float* __restrict__ W, short* __restrict__ Wt, int K, int N) {
    __shared__ float tile[64][65];
    int k0 = blockIdx.y * 64, n0 = blockIdx.x * 64;
    int tid = threadIdx.x;
    #pragma unroll
    for (int e = 0; e < 16; ++e) {
        int idx = e * 256 + tid;
        int r = idx >> 6, c = idx & 63;
        tile[r][c] = W[(size_t)(k0 + r) * N + n0 + c];
    }
    __syncthreads();
    #pragma unroll
    for (int e = 0; e < 16; ++e) {
        int idx = e * 256 + tid;
        int n = idx >> 6, k = idx & 63;
        Wt[(size_t)(n0 + n) * K + k0 + k] = (short)f2bf(tile[k][n]);
    }
}

// ---------------- fused QKV GEMM + bias + RoPE + head-split + V-transpose --
// qkv[t][n] = x[t][:] @ w[:, n] + b[n], then per 64-col head slice:
//   tensor 0/1 (Q/K): rope pairs (d, d+32) in-register -> bf16 [h][t][d]
//   tensor 2   (V):   LDS-transpose wave tile        -> bf16 [h][d][t]
// Block 256 = 4 waves (2x2), tile 128x128, BK=64. Blocks are single-tensor
// (768 = 6*128). Wave's 64-col slice = exactly one head.
__global__ __launch_bounds__(256) void gemm_qkv_rope_kernel(
    const short* __restrict__ A, const short* __restrict__ Bt,
    const float* __restrict__ bias, const float* __restrict__ ctab,
    const float* __restrict__ stab, short* __restrict__ Qout,
    short* __restrict__ Kout, short* __restrict__ Vtout) {
    __shared__ __align__(16) short smem[2 * 8 * 130 * 8];
    short* As = smem;
    short* Bs = smem + 8 * 130 * 8;
    int tid = threadIdx.x;
    int w = tid >> 6, l = tid & 63;
    int lr = l & 15, lg = l >> 4;
    int wm = w >> 1, wn = w & 1;
    int m0 = blockIdx.y * 128, n0 = blockIdx.x * 128;
    const int K = C_DIM, N = QKV_N;

    f32x4 acc[4][4] = {};

    for (int k0 = 0; k0 < K; k0 += 64) {
        __syncthreads();
        #pragma unroll
        for (int e = 0; e < 4; ++e) {
            int u = w * 4 + e;
            int kc = u >> 1, r0 = (u & 1) * 64;
            const short* srcA = A  + (size_t)(m0 + r0 + l) * K + k0 + kc * 8;
            const short* srcB = Bt + (size_t)(n0 + r0 + l) * K + k0 + kc * 8;
            gload_lds16(srcA, &As[(kc * 130 + r0) * 8]);
            gload_lds16(srcB, &Bs[(kc * 130 + r0) * 8]);
        }
        __syncthreads();
        #pragma unroll
        for (int ks = 0; ks < 2; ++ks) {
            short8 af[4], bf[4];
            #pragma unroll
            for (int mt = 0; mt < 4; ++mt)
                af[mt] = *(const short8*)&As[((ks * 4 + lg) * 130 + wm * 64 + mt * 16 + lr) * 8];
            #pragma unroll
            for (int nt = 0; nt < 4; ++nt)
                bf[nt] = *(const short8*)&Bs[((ks * 4 + lg) * 130 + wn * 64 + nt * 16 + lr) * 8];
            #pragma unroll
            for (int mt = 0; mt < 4; ++mt)
                #pragma unroll
                for (int nt = 0; nt < 4; ++nt)
                    acc[mt][nt] = __builtin_amdgcn_mfma_f32_16x16x32_bf16(
                        af[mt], bf[nt], acc[mt][nt], 0, 0, 0);
        }
    }

    __syncthreads();   // all waves done with As/Bs before V-scratch reuse

    int nc0 = n0 + wn * 64;            // wave's column base (one head)
    int tensor = nc0 / 768;            // 0=Q 1=K 2=V (uniform per wave/block)
    int h = (nc0 - tensor * 768) >> 6;
    int t0g = m0 + wm * 64;

    float bv[4];
    #pragma unroll
    for (int nt = 0; nt < 4; ++nt) bv[nt] = bias[nc0 + nt * 16 + lr];

    if (tensor < 2) {
        short* dst = (tensor == 0 ? Qout : Kout) + (size_t)h * T_SEQ * HD;
        float qs = (tensor == 0) ? 0.125f : 1.0f;
        #pragma unroll
        for (int mt = 0; mt < 4; ++mt)
            #pragma unroll
            for (int r = 0; r < 4; ++r) {
                int t = t0g + mt * 16 + lg * 4 + r;
                #pragma unroll
                for (int nt = 0; nt < 2; ++nt) {
                    int i = nt * 16 + lr;          // 0..31
                    float c = ctab[t * 32 + i];
                    float s = stab[t * 32 + i];
                    float lo = acc[mt][nt][r]     + bv[nt];
                    float hi = acc[mt][nt + 2][r] + bv[nt + 2];
                    dst[(size_t)t * HD + i]      = (short)f2bf((lo * c - hi * s) * qs);
                    dst[(size_t)t * HD + i + 32] = (short)f2bf((hi * c + lo * s) * qs);
                }
            }
    } else {
        // V: transpose 64x64 wave tile via per-wave LDS scratch region.
        // Element (d, tl) stored at chunk (tl>>3)^(d&7), offset tl&7.
        short* S = smem + w * 4096;
        #pragma unroll
        for (int mt = 0; mt < 4; ++mt)
            #pragma unroll
            for (int nt = 0; nt < 4; ++nt) {
                int d = nt * 16 + lr;
                #pragma unroll
                for (int r = 0; r < 4; ++r) {
                    int tl = mt * 16 + lg * 4 + r;
                    float v = acc[mt][nt][r] + bv[nt];
                    S[d * 64 + ((tl & 7) | (((tl >> 3) ^ (d & 7)) << 3))] =
                        (short)f2bf(v);
                }
            }
        asm volatile("s_waitcnt lgkmcnt(0)" ::: "memory");
        int cc = l & 7, db = l >> 3;
        #pragma unroll
        for (int i = 0; i < 8; ++i) {
            int d = db + i * 8;
            short8 v = *(const short8*)&S[d * 64 + ((cc ^ (d & 7)) << 3)];
            *(short8*)(Vtout + ((size_t)h * HD + d) * T_SEQ + t0g + cc * 8) = v;
        }
    }
}

// ---------------- bf16 MFMA GEMM: C[M][N] = A[M][K] @ Bt[N][K]^T + bias ----
__global__ __launch_bounds__(256) void gemm_bf16_kernel(
    const short* __restrict__ A, const short* __restrict__ Bt,
    const float* __restrict__ bias, float* __restrict__ C,
    int M, int N, int K) {
    __shared__ __align__(16) short As[8 * 130 * 8];
    __shared__ __align__(16) short Bs[8 * 130 * 8];
    int tid = threadIdx.x;
    int w = tid >> 6, l = tid & 63;
    int lr = l & 15, lg = l >> 4;
    int wm = w >> 1, wn = w & 1;
    int m0 = blockIdx.y * 128, n0 = blockIdx.x * 128;

    f32x4 acc[4][4] = {};

    for (int k0 = 0; k0 < K; k0 += 64) {
        __syncthreads();
        #pragma unroll
        for (int e = 0; e < 4; ++e) {
            int u = w * 4 + e;
            int kc = u >> 1, r0 = (u & 1) * 64;
            const short* srcA = A  + (size_t)(m0 + r0 + l) * K + k0 + kc * 8;
            const short* srcB = Bt + (size_t)(n0 + r0 + l) * K + k0 + kc * 8;
            gload_lds16(srcA, &As[(kc * 130 + r0) * 8]);
            gload_lds16(srcB, &Bs[(kc * 130 + r0) * 8]);
        }
        __syncthreads();
        #pragma unroll
        for (int ks = 0; ks < 2; ++ks) {
            short8 af[4], bf[4];
            #pragma unroll
            for (int mt = 0; mt < 4; ++mt)
                af[mt] = *(const short8*)&As[((ks * 4 + lg) * 130 + wm * 64 + mt * 16 + lr) * 8];
            #pragma unroll
            for (int nt = 0; nt < 4; ++nt)
                bf[nt] = *(const short8*)&Bs[((ks * 4 + lg) * 130 + wn * 64 + nt * 16 + lr) * 8];
            #pragma unroll
            for (int mt = 0; mt < 4; ++mt)
                #pragma unroll
                for (int nt = 0; nt < 4; ++nt)
                    acc[mt][nt] = __builtin_amdgcn_mfma_f32_16x16x32_bf16(
                        af[mt], bf[nt], acc[mt][nt], 0, 0, 0);
        }
    }

    #pragma unroll
    for (int mt = 0; mt < 4; ++mt)
        #pragma unroll
        for (int r = 0; r < 4; ++r) {
            int row = m0 + wm * 64 + mt * 16 + lg * 4 + r;
            #pragma unroll
            for (int nt = 0; nt < 4; ++nt) {
                int col = n0 + wn * 64 + nt * 16 + lr;
                C[(size_t)row * N + col] = acc[mt][nt][r] + bias[col];
            }
        }
}

// ---------------- causal flash attention, bf16 MFMA, split-K ---------------
// 960 jobs = 12 heads x {(qi, chunk)}: qi 0..7 -> 1 chunk, 8..15 -> 2,
// 16..23 -> 3, 24..31 -> 4 (CH=8 kv-tiles per chunk).
// Single-chunk jobs write final Yb; others write unnormalized O + (m,l).
__global__ __launch_bounds__(256) void attn_mfma_kernel(
    const bf16* __restrict__ Qp, const bf16* __restrict__ Kp,
    const bf16* __restrict__ Vtp, short* __restrict__ Yb,
    short* __restrict__ Opart, float* __restrict__ ml) {
    __shared__ __align__(16) short KsB[2][64 * 64];
    __shared__ __align__(16) short VtB[2][64 * 64];
    __shared__ __align__(16) short Pl[4][16 * 64];

    int tid = threadIdx.x;
    int w  = tid >> 6;
    int l  = tid & 63;
    int lr = l & 15;
    int lg = l >> 4;

    int job = (NJOBS - 1) - blockIdx.x;   // long-qi chunks dispatch first
    int h = job % NH;
    int u = job / NH;                     // 0..79
    int qi, c0;
    if (u < 8)       { qi = u;                      c0 = 0; }
    else if (u < 24) { int v = u - 8;  qi = 8  + (v >> 1); c0 = v & 1; }
    else if (u < 48) { int v = u - 24; qi = 16 + v / 3;    c0 = v - (v / 3) * 3; }
    else             { int v = u - 48; qi = 24 + (v >> 2); c0 = v & 3; }
    int kt0 = c0 * CH;
    int kt1 = kt0 + CH; if (kt1 > qi + 1) kt1 = qi + 1;
    int nch = (qi + CH) >> 3;             // ceil((qi+1)/8)
    int qt0 = qi * 64;

    const short* Qg  = (const short*)(Qp + (size_t)h * T_SEQ * HD);
    const short* Kg  = (const short*)(Kp + (size_t)h * T_SEQ * HD);
    const short* Vtg = (const short*)(Vtp + (size_t)h * HD * T_SEQ);

    int qrow = qt0 + w * 16 + lr;
    short8 qf0 = *(const short8*)(Qg + (size_t)qrow * HD + lg * 8);
    short8 qf1 = *(const short8*)(Qg + (size_t)qrow * HD + 32 + lg * 8);

    int srow = l >> 3;
    int cx   = (l & 7) ^ srow;            // inverse-swizzled source chunk

    auto stage = [&](int buf, int kt) {
        int k0 = kt * 64;
        #pragma unroll
        for (int e = 0; e < 2; ++e) {
            int r = e * 32 + w * 8 + srow;
            gload_lds16(Kg + (size_t)(k0 + r) * HD + cx * 8,
                        &KsB[buf][(e * 256 + w * 64) * 8]);
            gload_lds16(Vtg + (size_t)r * T_SEQ + k0 + cx * 8,
                        &VtB[buf][(e * 256 + w * 64) * 8]);
        }
    };

    f32x4 o[4] = {};
    float m = -INFINITY, lsum = 0.f;

    stage(0, kt0);

    for (int kt = kt0; kt < kt1; ++kt) {
        int cur = (kt - kt0) & 1;
        if (kt + 1 < kt1) {
            stage(1 - cur, kt + 1);
            asm volatile("s_waitcnt vmcnt(4)" ::: "memory");
        } else {
            asm volatile("s_waitcnt vmcnt(0)" ::: "memory");
        }
        __builtin_amdgcn_s_barrier();

        const short* Ks = KsB[cur];
        const short* Vt = VtB[cur];

        f32x4 c[4];
        #pragma unroll
        for (int mt = 0; mt < 4; ++mt) {
            c[mt] = (f32x4){0.f, 0.f, 0.f, 0.f};
            int row = mt * 16 + lr;
            #pragma unroll
            for (int ks = 0; ks < 2; ++ks) {
                short8 af = *(const short8*)(&Ks[row * 64 + (((ks * 4 + lg) ^ (row & 7)) << 3)]);
                c[mt] = __builtin_amdgcn_mfma_f32_16x16x32_bf16(af, ks ? qf1 : qf0, c[mt], 0, 0, 0);
            }
        }

        float p[16];
        float smax = -INFINITY;
        if (kt == qi) {                    // diagonal tile: causal mask
            int qg = qt0 + w * 16 + lr;
            int k0 = kt * 64;
            #pragma unroll
            for (int mt = 0; mt < 4; ++mt)
                #pragma unroll
                for (int r = 0; r < 4; ++r) {
                    float s = c[mt][r];
                    if (k0 + mt * 16 + lg * 4 + r > qg) s = -INFINITY;
                    p[mt * 4 + r] = s;
                    smax = fmaxf(smax, s);
                }
        } else {
            #pragma unroll
            for (int mt = 0; mt < 4; ++mt)
                #pragma unroll
                for (int r = 0; r < 4; ++r) {
                    float s = c[mt][r];
                    p[mt * 4 + r] = s;
                    smax = fmaxf(smax, s);
                }
        }
        smax = fmaxf(smax, __shfl_xor(smax, 16));
        smax = fmaxf(smax, __shfl_xor(smax, 32));
        float mnew = fmaxf(m, smax);
        float alpha = __expf(m - mnew);
        float ps = 0.f;
        #pragma unroll
        for (int i = 0; i < 16; ++i) { p[i] = __expf(p[i] - mnew); ps += p[i]; }
        ps += __shfl_xor(ps, 16);
        ps += __shfl_xor(ps, 32);
        lsum = lsum * alpha + ps;
        m = mnew;

        #pragma unroll
        for (int r = 0; r < 4; ++r) {
            float ar = __shfl(alpha, lg * 4 + r);
            #pragma unroll
            for (int nt = 0; nt < 4; ++nt) o[nt][r] *= ar;
        }

        short* Pw = &Pl[w][0];
        #pragma unroll
        for (int mt = 0; mt < 4; ++mt)
            #pragma unroll
            for (int rh = 0; rh < 2; ++rh) {
                unsigned int uu = f2bf(p[mt * 4 + 2 * rh]) | (f2bf(p[mt * 4 + 2 * rh + 1]) << 16);
                int chunk = 2 * mt + (lg >> 1);
                *(unsigned int*)(&Pw[lr * 64 + ((chunk ^ (lr & 7)) << 3)
                                     + 4 * (lg & 1) + 2 * rh]) = uu;
            }
        asm volatile("" ::: "memory");

        #pragma unroll
        for (int ks = 0; ks < 2; ++ks) {
            short8 pf = *(const short8*)(&Pw[lr * 64 + (((ks * 4 + lg) ^ (lr & 7)) << 3)]);
            #pragma unroll
            for (int nt = 0; nt < 4; ++nt) {
                int vrow = nt * 16 + lr;
                short8 vf = *(const short8*)(&Vt[vrow * 64 + (((ks * 4 + lg) ^ (vrow & 7)) << 3)]);
                o[nt] = __builtin_amdgcn_mfma_f32_16x16x32_bf16(pf, vf, o[nt], 0, 0, 0);
            }
        }
        __builtin_amdgcn_s_barrier();
    }

    if (nch == 1) {
        float invl = 1.f / lsum;
        #pragma unroll
        for (int r = 0; r < 4; ++r) {
            float ir = __shfl(invl, lg * 4 + r);
            int row = qt0 + w * 16 + lg * 4 + r;
            #pragma unroll
            for (int nt = 0; nt < 4; ++nt)
                Yb[(size_t)row * C_DIM + h * HD + nt * 16 + lr] =
                    (short)f2bf(o[nt][r] * ir);
        }
    } else {
        if (lg == 0) {
            ml[(size_t)job * 128 + w * 16 + lr] = m;
            ml[(size_t)job * 128 + 64 + w * 16 + lr] = lsum;
        }
        #pragma unroll
        for (int r = 0; r < 4; ++r) {
            int row = w * 16 + lg * 4 + r;
            #pragma unroll
            for (int nt = 0; nt < 4; ++nt)
                Opart[(size_t)job * 4096 + row * 64 + nt * 16 + lr] =
                    (short)f2bf(o[nt][r]);
        }
    }
}

// ---------------- combine split-K partials (qi >= 8) -----------------------
__global__ __launch_bounds__(256) void combine_kernel(
    const short* __restrict__ Opart, const float* __restrict__ ml,
    short* __restrict__ Yb) {
    int job = blockIdx.x;
    int h  = job % NH;
    int qi = 8 + job / NH;
    int nch = (qi + CH) >> 3;
    int u0;
    if (qi < 16)      u0 = 8  + (qi - 8) * 2;
    else if (qi < 24) u0 = 24 + (qi - 16) * 3;
    else              u0 = 48 + (qi - 24) * 4;

    int tid = threadIdx.x;
    int row = tid >> 2;
    int qp  = tid & 3;

    float mm[4], ll[4];
    float M = -INFINITY;
    #pragma unroll
    for (int c = 0; c < 4; ++c) {
        mm[c] = -INFINITY; ll[c] = 0.f;
        if (c < nch) {
            size_t pidx = (size_t)(u0 + c) * NH + h;
            mm[c] = ml[pidx * 128 + row];
            ll[c] = ml[pidx * 128 + 64 + row];
            M = fmaxf(M, mm[c]);
        }
    }
    float acc[16] = {};
    float L = 0.f;
    #pragma unroll
    for (int c = 0; c < 4; ++c) {
        if (c < nch) {
            float wgt = __expf(mm[c] - M);
            L += ll[c] * wgt;
            const short* op = Opart + ((size_t)(u0 + c) * NH + h) * 4096
                            + row * 64 + qp * 16;
            short8 a = *(const short8*)op;
            short8 b = *(const short8*)(op + 8);
            #pragma unroll
            for (int j = 0; j < 8; ++j) {
                acc[j]     += wgt * bf2f(a[j]);
                acc[8 + j] += wgt * bf2f(b[j]);
            }
        }
    }
    float invL = 1.f / L;
    short8 oa, ob;
    #pragma unroll
    for (int j = 0; j < 8; ++j) {
        oa[j] = (short)f2bf(acc[j] * invL);
        ob[j] = (short)f2bf(acc[8 + j] * invL);
    }
    short* dst = Yb + (size_t)(qi * 64 + row) * C_DIM + h * HD + qp * 16;
    *(short8*)dst = oa;
    *(short8*)(dst + 8) = ob;
}

extern "C" void kernel_launch(void* const* d_in, const int* in_sizes, int n_in,
                              void* d_out, int out_size, void* d_ws, size_t ws_size,
                              hipStream_t stream) {
    const float* x      = (const float*)d_in[0];
    const float* w_qkv  = (const float*)d_in[1];
    const float* b_qkv  = (const float*)d_in[2];
    const float* w_proj = (const float*)d_in[3];
    const float* b_proj = (const float*)d_in[4];
    float* out = (float*)d_out;

    float* ws = (float*)d_ws;
    // All regions disjoint (no f32 qkv intermediate anymore). ~29.3 MB total.
    short* yb     = (short*)ws;                 // @0        1,572,864 sh
    short* wprojT = (short*)(ws + 786432);      //           589,824 sh
    short* Opart  = (short*)(ws + 1081344);     //           960*4096 sh
    float* mlbuf  = ws + 3047424;               //           960*128 f
    short* Qh     = (short*)(ws + 3170304);     //           1,572,864 sh
    short* Kh     = (short*)(ws + 3956736);
    short* Vt     = (short*)(ws + 4743168);     // [h][d][t]
    float* ctab   = ws + 5529600;               //           65,536 f
    float* stab   = ws + 5595136;
    short* xb     = (short*)(ws + 5660672);     //           1,572,864 sh
    short* wqkvT  = (short*)(ws + 6447104);     //           1,769,472 sh

    rope_table_kernel<<<256, 256, 0, stream>>>(ctab, stab);

    convert_f32_bf16_kernel<<<(T_SEQ * C_DIM) / 1024, 256, 0, stream>>>(x, xb, T_SEQ * C_DIM);

    dim3 gt1(QKV_N / 64, C_DIM / 64);
    transpose_f32_bf16_kernel<<<gt1, 256, 0, stream>>>(w_qkv, wqkvT, C_DIM, QKV_N);

    dim3 g1(QKV_N / 128, T_SEQ / 128);
    gemm_qkv_rope_kernel<<<g1, 256, 0, stream>>>(xb, wqkvT, b_qkv, ctab, stab,
                                                 Qh, Kh, Vt);

    dim3 gt2(C_DIM / 64, C_DIM / 64);
    transpose_f32_bf16_kernel<<<gt2, 256, 0, stream>>>(w_proj, wprojT, C_DIM, C_DIM);

    attn_mfma_kernel<<<NJOBS, 256, 0, stream>>>((const bf16*)Qh, (const bf16*)Kh,
                                                (const bf16*)Vt, yb, Opart, mlbuf);

    combine_kernel<<<NH * 24, 256, 0, stream>>>(Opart, mlbuf, yb);

    dim3 g4(C_DIM / 128, T_SEQ / 128);
    gemm_bf16_kernel<<<g4, 256, 0, stream>>>(yb, wprojT, b_proj, out, T_SEQ, C_DIM, C_DIM);
}

// Round 7
// 83.249 us; speedup vs baseline: 8.7313x; 1.1977x over previous
//
#include <hip/hip_runtime.h>
#include <hip/hip_bf16.h>
#include <math.h>

#define T_SEQ 2048
#define C_DIM 768
#define NH    12
#define HD    64
#define QKV_N 2304
#define CH    4          // kv-tiles per attention chunk (split-K)
#define NJOBS 1728       // 12 heads x 144 (qi,chunk) pairs

typedef __attribute__((ext_vector_type(8))) short short8;
typedef __attribute__((ext_vector_type(4))) short short4_t;
typedef __attribute__((ext_vector_type(4))) float f32x4;
typedef __hip_bfloat16 bf16;

static __device__ __forceinline__ unsigned int f2bf(float x) {
    bf16 b = __float2bfloat16(x);
    return (unsigned int)*reinterpret_cast<unsigned short*>(&b);
}
static __device__ __forceinline__ float bf2f(short u) {
    unsigned int v = ((unsigned int)(unsigned short)u) << 16;
    return *reinterpret_cast<float*>(&v);
}

static __device__ __forceinline__ void gload_lds16(const void* g, void* l) {
    __builtin_amdgcn_global_load_lds(
        (const __attribute__((address_space(1))) void*)g,
        (__attribute__((address_space(3))) void*)l, 16, 0, 0);
}

// ---------------- fused prep: convert x | transpose w_qkv | transpose w_proj
//                  | rope tables.  2368 blocks, range-dispatched. -----------
static __device__ __forceinline__ void transpose_tile(
    const float* __restrict__ W, short* __restrict__ Wt, int K, int N,
    int bx, int by, float* tile /* [64][65] */) {
    int k0 = by * 64, n0 = bx * 64;
    int tid = threadIdx.x;
    #pragma unroll
    for (int e = 0; e < 16; ++e) {
        int idx = e * 256 + tid;
        int r = idx >> 6, c = idx & 63;
        tile[r * 65 + c] = W[(size_t)(k0 + r) * N + n0 + c];
    }
    __syncthreads();
    #pragma unroll
    for (int e = 0; e < 16; ++e) {
        int idx = e * 256 + tid;
        int n = idx >> 6, k = idx & 63;
        Wt[(size_t)(n0 + n) * K + k0 + k] = (short)f2bf(tile[k * 65 + n]);
    }
}

__global__ __launch_bounds__(256) void prep_kernel(
    const float* __restrict__ x, const float* __restrict__ w_qkv,
    const float* __restrict__ w_proj, short* __restrict__ xb,
    short* __restrict__ wqkvT, short* __restrict__ wprojT,
    float* __restrict__ ctab, float* __restrict__ stab) {
    __shared__ float tile[64 * 65];
    int b = blockIdx.x;
    int tid = threadIdx.x;
    if (b < 1536) {                       // convert x -> bf16 (1536*1024 elems)
        int idx = (b * 256 + tid) * 4;
        float4 v = *(const float4*)(x + idx);
        short4_t o;
        o[0] = (short)f2bf(v.x); o[1] = (short)f2bf(v.y);
        o[2] = (short)f2bf(v.z); o[3] = (short)f2bf(v.w);
        *(short4_t*)(xb + idx) = o;
    } else if (b < 1968) {                // w_qkv [768][2304] -> [2304][768]
        int i = b - 1536;
        transpose_tile(w_qkv, wqkvT, C_DIM, QKV_N, i % 36, i / 36, tile);
    } else if (b < 2112) {                // w_proj [768][768] -> [768][768]^T
        int i = b - 1968;
        transpose_tile(w_proj, wprojT, C_DIM, C_DIM, i % 12, i / 12, tile);
    } else {                              // rope tables (256 blocks)
        int idx = (b - 2112) * 256 + tid;
        int p = idx >> 5;
        int i = idx & 31;
        float invf = exp2f(-(float)i * (0.03125f * 13.287712379549449f));
        float f = (float)p * invf;
        ctab[idx] = cosf(f);
        stab[idx] = sinf(f);
    }
}

// ---------------- fused QKV GEMM + bias + RoPE + head-split + V-transpose --
__global__ __launch_bounds__(256) void gemm_qkv_rope_kernel(
    const short* __restrict__ A, const short* __restrict__ Bt,
    const float* __restrict__ bias, const float* __restrict__ ctab,
    const float* __restrict__ stab, short* __restrict__ Qout,
    short* __restrict__ Kout, short* __restrict__ Vtout) {
    __shared__ __align__(16) short smem[2 * 8 * 130 * 8];
    short* As = smem;
    short* Bs = smem + 8 * 130 * 8;
    int tid = threadIdx.x;
    int w = tid >> 6, l = tid & 63;
    int lr = l & 15, lg = l >> 4;
    int wm = w >> 1, wn = w & 1;
    int m0 = blockIdx.y * 128, n0 = blockIdx.x * 128;
    const int K = C_DIM;

    f32x4 acc[4][4] = {};

    for (int k0 = 0; k0 < K; k0 += 64) {
        __syncthreads();
        #pragma unroll
        for (int e = 0; e < 4; ++e) {
            int u = w * 4 + e;
            int kc = u >> 1, r0 = (u & 1) * 64;
            const short* srcA = A  + (size_t)(m0 + r0 + l) * K + k0 + kc * 8;
            const short* srcB = Bt + (size_t)(n0 + r0 + l) * K + k0 + kc * 8;
            gload_lds16(srcA, &As[(kc * 130 + r0) * 8]);
            gload_lds16(srcB, &Bs[(kc * 130 + r0) * 8]);
        }
        __syncthreads();
        #pragma unroll
        for (int ks = 0; ks < 2; ++ks) {
            short8 af[4], bf[4];
            #pragma unroll
            for (int mt = 0; mt < 4; ++mt)
                af[mt] = *(const short8*)&As[((ks * 4 + lg) * 130 + wm * 64 + mt * 16 + lr) * 8];
            #pragma unroll
            for (int nt = 0; nt < 4; ++nt)
                bf[nt] = *(const short8*)&Bs[((ks * 4 + lg) * 130 + wn * 64 + nt * 16 + lr) * 8];
            #pragma unroll
            for (int mt = 0; mt < 4; ++mt)
                #pragma unroll
                for (int nt = 0; nt < 4; ++nt)
                    acc[mt][nt] = __builtin_amdgcn_mfma_f32_16x16x32_bf16(
                        af[mt], bf[nt], acc[mt][nt], 0, 0, 0);
        }
    }

    __syncthreads();   // all waves done with As/Bs before V-scratch reuse

    int nc0 = n0 + wn * 64;            // wave's column base (one head)
    int tensor = nc0 / 768;            // 0=Q 1=K 2=V (uniform per wave)
    int h = (nc0 - tensor * 768) >> 6;
    int t0g = m0 + wm * 64;

    float bv[4];
    #pragma unroll
    for (int nt = 0; nt < 4; ++nt) bv[nt] = bias[nc0 + nt * 16 + lr];

    if (tensor < 2) {
        short* dst = (tensor == 0 ? Qout : Kout) + (size_t)h * T_SEQ * HD;
        float qs = (tensor == 0) ? 0.125f : 1.0f;
        #pragma unroll
        for (int mt = 0; mt < 4; ++mt)
            #pragma unroll
            for (int r = 0; r < 4; ++r) {
                int t = t0g + mt * 16 + lg * 4 + r;
                #pragma unroll
                for (int nt = 0; nt < 2; ++nt) {
                    int i = nt * 16 + lr;          // 0..31
                    float c = ctab[t * 32 + i];
                    float s = stab[t * 32 + i];
                    float lo = acc[mt][nt][r]     + bv[nt];
                    float hi = acc[mt][nt + 2][r] + bv[nt + 2];
                    dst[(size_t)t * HD + i]      = (short)f2bf((lo * c - hi * s) * qs);
                    dst[(size_t)t * HD + i + 32] = (short)f2bf((hi * c + lo * s) * qs);
                }
            }
    } else {
        // V: transpose 64x64 wave tile via per-wave LDS scratch region.
        short* S = smem + w * 4096;
        #pragma unroll
        for (int mt = 0; mt < 4; ++mt)
            #pragma unroll
            for (int nt = 0; nt < 4; ++nt) {
                int d = nt * 16 + lr;
                #pragma unroll
                for (int r = 0; r < 4; ++r) {
                    int tl = mt * 16 + lg * 4 + r;
                    float v = acc[mt][nt][r] + bv[nt];
                    S[d * 64 + ((tl & 7) | (((tl >> 3) ^ (d & 7)) << 3))] =
                        (short)f2bf(v);
                }
            }
        asm volatile("s_waitcnt lgkmcnt(0)" ::: "memory");
        int cc = l & 7, db = l >> 3;
        #pragma unroll
        for (int i = 0; i < 8; ++i) {
            int d = db + i * 8;
            short8 v = *(const short8*)&S[d * 64 + ((cc ^ (d & 7)) << 3)];
            *(short8*)(Vtout + ((size_t)h * HD + d) * T_SEQ + t0g + cc * 8) = v;
        }
    }
}

// ---------------- proj GEMM, 64x64 tile (384 blocks): C = A @ Bt^T + bias --
// Block 256 = 4 waves (2x2), each wave one 32x32 quadrant. BK=64, K=N=768.
__global__ __launch_bounds__(256) void gemm_proj_kernel(
    const short* __restrict__ A, const short* __restrict__ Bt,
    const float* __restrict__ bias, float* __restrict__ C) {
    const int K = C_DIM, N = C_DIM;
    __shared__ __align__(16) short As[8 * 66 * 8];
    __shared__ __align__(16) short Bs[8 * 66 * 8];
    int tid = threadIdx.x;
    int w = tid >> 6, l = tid & 63;
    int lr = l & 15, lg = l >> 4;
    int wm = w >> 1, wn = w & 1;
    int m0 = blockIdx.y * 64, n0 = blockIdx.x * 64;

    f32x4 acc[2][2] = {};

    for (int k0 = 0; k0 < K; k0 += 64) {
        __syncthreads();
        #pragma unroll
        for (int e = 0; e < 2; ++e) {
            int kc = w * 2 + e;                 // wave-uniform dest base
            gload_lds16(A  + (size_t)(m0 + l) * K + k0 + kc * 8, &As[kc * 66 * 8]);
            gload_lds16(Bt + (size_t)(n0 + l) * K + k0 + kc * 8, &Bs[kc * 66 * 8]);
        }
        __syncthreads();
        #pragma unroll
        for (int ks = 0; ks < 2; ++ks) {
            short8 af[2], bf[2];
            #pragma unroll
            for (int mt = 0; mt < 2; ++mt)
                af[mt] = *(const short8*)&As[((ks * 4 + lg) * 66 + wm * 32 + mt * 16 + lr) * 8];
            #pragma unroll
            for (int nt = 0; nt < 2; ++nt)
                bf[nt] = *(const short8*)&Bs[((ks * 4 + lg) * 66 + wn * 32 + nt * 16 + lr) * 8];
            #pragma unroll
            for (int mt = 0; mt < 2; ++mt)
                #pragma unroll
                for (int nt = 0; nt < 2; ++nt)
                    acc[mt][nt] = __builtin_amdgcn_mfma_f32_16x16x32_bf16(
                        af[mt], bf[nt], acc[mt][nt], 0, 0, 0);
        }
    }

    #pragma unroll
    for (int mt = 0; mt < 2; ++mt)
        #pragma unroll
        for (int r = 0; r < 4; ++r) {
            int row = m0 + wm * 32 + mt * 16 + lg * 4 + r;
            #pragma unroll
            for (int nt = 0; nt < 2; ++nt) {
                int col = n0 + wn * 32 + nt * 16 + lr;
                C[(size_t)row * N + col] = acc[mt][nt][r] + bias[col];
            }
        }
}

// ---------------- causal flash attention, bf16 MFMA, split-K (CH=4) --------
// 1728 jobs = 12 heads x 144 (qi,chunk).  Group g = qi>>2 has nch = g+1
// chunks per row-tile; group g starts at u = 2g(g+1).
__global__ __launch_bounds__(256) void attn_mfma_kernel(
    const bf16* __restrict__ Qp, const bf16* __restrict__ Kp,
    const bf16* __restrict__ Vtp, short* __restrict__ Yb,
    short* __restrict__ Opart, float* __restrict__ ml) {
    __shared__ __align__(16) short KsB[2][64 * 64];
    __shared__ __align__(16) short VtB[2][64 * 64];
    __shared__ __align__(16) short Pl[4][16 * 64];

    int tid = threadIdx.x;
    int w  = tid >> 6;
    int l  = tid & 63;
    int lr = l & 15;
    int lg = l >> 4;

    int job = (NJOBS - 1) - blockIdx.x;   // long-qi chunks dispatch first
    int h = job % NH;
    int u = job / NH;                     // 0..143
    int g = 0;
    while (u >= 2 * (g + 1) * (g + 2)) ++g;
    int v  = u - 2 * g * (g + 1);
    int jq = v / (g + 1);
    int qi = 4 * g + jq;
    int c0 = v - jq * (g + 1);
    int nch = g + 1;
    int kt0 = c0 * CH;
    int kt1 = kt0 + CH; if (kt1 > qi + 1) kt1 = qi + 1;
    int qt0 = qi * 64;

    const short* Qg  = (const short*)(Qp + (size_t)h * T_SEQ * HD);
    const short* Kg  = (const short*)(Kp + (size_t)h * T_SEQ * HD);
    const short* Vtg = (const short*)(Vtp + (size_t)h * HD * T_SEQ);

    int qrow = qt0 + w * 16 + lr;
    short8 qf0 = *(const short8*)(Qg + (size_t)qrow * HD + lg * 8);
    short8 qf1 = *(const short8*)(Qg + (size_t)qrow * HD + 32 + lg * 8);

    int srow = l >> 3;
    int cx   = (l & 7) ^ srow;            // inverse-swizzled source chunk

    auto stage = [&](int buf, int kt) {
        int k0 = kt * 64;
        #pragma unroll
        for (int e = 0; e < 2; ++e) {
            int r = e * 32 + w * 8 + srow;
            gload_lds16(Kg + (size_t)(k0 + r) * HD + cx * 8,
                        &KsB[buf][(e * 256 + w * 64) * 8]);
            gload_lds16(Vtg + (size_t)r * T_SEQ + k0 + cx * 8,
                        &VtB[buf][(e * 256 + w * 64) * 8]);
        }
    };

    f32x4 o[4] = {};
    float m = -INFINITY, lsum = 0.f;

    stage(0, kt0);

    for (int kt = kt0; kt < kt1; ++kt) {
        int cur = (kt - kt0) & 1;
        if (kt + 1 < kt1) {
            stage(1 - cur, kt + 1);
            asm volatile("s_waitcnt vmcnt(4)" ::: "memory");
        } else {
            asm volatile("s_waitcnt vmcnt(0)" ::: "memory");
        }
        __builtin_amdgcn_s_barrier();

        const short* Ks = KsB[cur];
        const short* Vt = VtB[cur];

        f32x4 c[4];
        #pragma unroll
        for (int mt = 0; mt < 4; ++mt) {
            c[mt] = (f32x4){0.f, 0.f, 0.f, 0.f};
            int row = mt * 16 + lr;
            #pragma unroll
            for (int ks = 0; ks < 2; ++ks) {
                short8 af = *(const short8*)(&Ks[row * 64 + (((ks * 4 + lg) ^ (row & 7)) << 3)]);
                c[mt] = __builtin_amdgcn_mfma_f32_16x16x32_bf16(af, ks ? qf1 : qf0, c[mt], 0, 0, 0);
            }
        }

        float p[16];
        float smax = -INFINITY;
        if (kt == qi) {                    // diagonal tile: causal mask
            int qg = qt0 + w * 16 + lr;
            int k0 = kt * 64;
            #pragma unroll
            for (int mt = 0; mt < 4; ++mt)
                #pragma unroll
                for (int r = 0; r < 4; ++r) {
                    float s = c[mt][r];
                    if (k0 + mt * 16 + lg * 4 + r > qg) s = -INFINITY;
                    p[mt * 4 + r] = s;
                    smax = fmaxf(smax, s);
                }
        } else {
            #pragma unroll
            for (int mt = 0; mt < 4; ++mt)
                #pragma unroll
                for (int r = 0; r < 4; ++r) {
                    float s = c[mt][r];
                    p[mt * 4 + r] = s;
                    smax = fmaxf(smax, s);
                }
        }
        smax = fmaxf(smax, __shfl_xor(smax, 16));
        smax = fmaxf(smax, __shfl_xor(smax, 32));
        float mnew = fmaxf(m, smax);
        float alpha = __expf(m - mnew);
        float ps = 0.f;
        #pragma unroll
        for (int i = 0; i < 16; ++i) { p[i] = __expf(p[i] - mnew); ps += p[i]; }
        ps += __shfl_xor(ps, 16);
        ps += __shfl_xor(ps, 32);
        lsum = lsum * alpha + ps;
        m = mnew;

        #pragma unroll
        for (int r = 0; r < 4; ++r) {
            float ar = __shfl(alpha, lg * 4 + r);
            #pragma unroll
            for (int nt = 0; nt < 4; ++nt) o[nt][r] *= ar;
        }

        short* Pw = &Pl[w][0];
        #pragma unroll
        for (int mt = 0; mt < 4; ++mt)
            #pragma unroll
            for (int rh = 0; rh < 2; ++rh) {
                unsigned int uu = f2bf(p[mt * 4 + 2 * rh]) | (f2bf(p[mt * 4 + 2 * rh + 1]) << 16);
                int chunk = 2 * mt + (lg >> 1);
                *(unsigned int*)(&Pw[lr * 64 + ((chunk ^ (lr & 7)) << 3)
                                     + 4 * (lg & 1) + 2 * rh]) = uu;
            }
        asm volatile("" ::: "memory");

        #pragma unroll
        for (int ks = 0; ks < 2; ++ks) {
            short8 pf = *(const short8*)(&Pw[lr * 64 + (((ks * 4 + lg) ^ (lr & 7)) << 3)]);
            #pragma unroll
            for (int nt = 0; nt < 4; ++nt) {
                int vrow = nt * 16 + lr;
                short8 vf = *(const short8*)(&Vt[vrow * 64 + (((ks * 4 + lg) ^ (vrow & 7)) << 3)]);
                o[nt] = __builtin_amdgcn_mfma_f32_16x16x32_bf16(pf, vf, o[nt], 0, 0, 0);
            }
        }
        __builtin_amdgcn_s_barrier();
    }

    if (nch == 1) {
        float invl = 1.f / lsum;
        #pragma unroll
        for (int r = 0; r < 4; ++r) {
            float ir = __shfl(invl, lg * 4 + r);
            int row = qt0 + w * 16 + lg * 4 + r;
            #pragma unroll
            for (int nt = 0; nt < 4; ++nt)
                Yb[(size_t)row * C_DIM + h * HD + nt * 16 + lr] =
                    (short)f2bf(o[nt][r] * ir);
        }
    } else {
        if (lg == 0) {
            ml[(size_t)job * 128 + w * 16 + lr] = m;
            ml[(size_t)job * 128 + 64 + w * 16 + lr] = lsum;
        }
        #pragma unroll
        for (int r = 0; r < 4; ++r) {
            int row = w * 16 + lg * 4 + r;
            #pragma unroll
            for (int nt = 0; nt < 4; ++nt)
                Opart[(size_t)job * 4096 + row * 64 + nt * 16 + lr] =
                    (short)f2bf(o[nt][r]);
        }
    }
}

// ---------------- combine split-K partials (qi >= 4, up to 8 chunks) -------
__global__ __launch_bounds__(256) void combine_kernel(
    const short* __restrict__ Opart, const float* __restrict__ ml,
    short* __restrict__ Yb) {
    int job = blockIdx.x;                 // 12 heads x 28 qi (4..31)
    int h  = job % NH;
    int qi = 4 + job / NH;
    int g  = qi >> 2;
    int nch = g + 1;
    int u0 = (g + 1) * (qi - 2 * g);

    int tid = threadIdx.x;
    int row = tid >> 2;
    int qp  = tid & 3;

    float mm[8], ll[8];
    float M = -INFINITY;
    #pragma unroll
    for (int c = 0; c < 8; ++c) {
        mm[c] = -INFINITY; ll[c] = 0.f;
        if (c < nch) {
            size_t pidx = (size_t)(u0 + c) * NH + h;
            mm[c] = ml[pidx * 128 + row];
            ll[c] = ml[pidx * 128 + 64 + row];
            M = fmaxf(M, mm[c]);
        }
    }
    float acc[16] = {};
    float L = 0.f;
    #pragma unroll
    for (int c = 0; c < 8; ++c) {
        if (c < nch) {
            float wgt = __expf(mm[c] - M);
            L += ll[c] * wgt;
            const short* op = Opart + ((size_t)(u0 + c) * NH + h) * 4096
                            + row * 64 + qp * 16;
            short8 a = *(const short8*)op;
            short8 b = *(const short8*)(op + 8);
            #pragma unroll
            for (int j = 0; j < 8; ++j) {
                acc[j]     += wgt * bf2f(a[j]);
                acc[8 + j] += wgt * bf2f(b[j]);
            }
        }
    }
    float invL = 1.f / L;
    short8 oa, ob;
    #pragma unroll
    for (int j = 0; j < 8; ++j) {
        oa[j] = (short)f2bf(acc[j] * invL);
        ob[j] = (short)f2bf(acc[8 + j] * invL);
    }
    short* dst = Yb + (size_t)(qi * 64 + row) * C_DIM + h * HD + qp * 16;
    *(short8*)dst = oa;
    *(short8*)(dst + 8) = ob;
}

extern "C" void kernel_launch(void* const* d_in, const int* in_sizes, int n_in,
                              void* d_out, int out_size, void* d_ws, size_t ws_size,
                              hipStream_t stream) {
    const float* x      = (const float*)d_in[0];
    const float* w_qkv  = (const float*)d_in[1];
    const float* b_qkv  = (const float*)d_in[2];
    const float* w_proj = (const float*)d_in[3];
    const float* b_proj = (const float*)d_in[4];
    float* out = (float*)d_out;

    float* ws = (float*)d_ws;
    short* yb     = (short*)ws;                 // 1,572,864 sh
    short* wprojT = (short*)(ws + 786432);      // 589,824 sh
    short* Opart  = (short*)(ws + 1081344);     // 1728*4096 sh
    float* mlbuf  = ws + 4620288;               // 1728*128 f
    short* Qh     = (short*)(ws + 4841472);     // 1,572,864 sh
    short* Kh     = (short*)(ws + 5627904);
    short* Vt     = (short*)(ws + 6414336);     // [h][d][t]
    float* ctab   = ws + 7200768;               // 65,536 f
    float* stab   = ws + 7266304;
    short* xb     = (short*)(ws + 7331840);     // 1,572,864 sh
    short* wqkvT  = (short*)(ws + 8118272);     // 1,769,472 sh

    prep_kernel<<<2368, 256, 0, stream>>>(x, w_qkv, w_proj, xb, wqkvT, wprojT,
                                          ctab, stab);

    dim3 g1(QKV_N / 128, T_SEQ / 128);
    gemm_qkv_rope_kernel<<<g1, 256, 0, stream>>>(xb, wqkvT, b_qkv, ctab, stab,
                                                 Qh, Kh, Vt);

    attn_mfma_kernel<<<NJOBS, 256, 0, stream>>>((const bf16*)Qh, (const bf16*)Kh,
                                                (const bf16*)Vt, yb, Opart, mlbuf);

    combine_kernel<<<NH * 28, 256, 0, stream>>>(Opart, mlbuf, yb);

    dim3 g4(C_DIM / 64, T_SEQ / 64);
    gemm_proj_kernel<<<g4, 256, 0, stream>>>(yb, wprojT, b_proj, out);
}